// Round 9
// baseline (2557.235 us; speedup 1.0000x reference)
//
#include <hip/hip_runtime.h>
#include <math.h>

#define NN 512
#define EMBD 10
#define HH 64
#define DINV 2
#define CIN 66
#define TT 12
#define BB 16
#define LH 130
#define LG 520
#define PART ((size_t)BB * NN * CIN)

typedef __attribute__((ext_vector_type(8))) short short8;
typedef __attribute__((ext_vector_type(4))) float f32x4;

__device__ __forceinline__ float sigmoidf_(float x) { return 1.f / (1.f + __expf(-x)); }
__device__ __forceinline__ float tanhf_(float x)    { return 1.f - 2.f / (1.f + __expf(2.f * x)); }
__device__ __forceinline__ float bl_(unsigned p) { return __uint_as_float(p << 16); }
__device__ __forceinline__ float bh_(unsigned p) { return __uint_as_float(p & 0xffff0000u); }
__device__ __forceinline__ unsigned bf16rne_(float f) {
    unsigned u = __float_as_uint(f);
    u += 0x7fff + ((u >> 16) & 1);
    return u >> 16;
}
__device__ __forceinline__ void split_(float v, unsigned& hi, unsigned& lo) {
    hi = bf16rne_(v);
    float hif = __uint_as_float(hi << 16);
    lo = bf16rne_(v - hif);
}

// ---------------- S_base = softmax(relu(emb @ emb^T)) ----------------
__global__ __launch_bounds__(256) void sbase_kernel(const float* __restrict__ emb,
                                                    float* __restrict__ Sb) {
    const int n = blockIdx.x;
    const int tid = threadIdx.x;
    __shared__ float en[EMBD];
    __shared__ float redw[4];
    if (tid < EMBD) en[tid] = emb[n * EMBD + tid];
    __syncthreads();
    float v[2];
    #pragma unroll
    for (int q = 0; q < 2; q++) {
        int m = tid + q * 256;
        float s = 0.f;
        #pragma unroll
        for (int d = 0; d < EMBD; d++) s += en[d] * emb[m * EMBD + d];
        v[q] = fmaxf(s, 0.f);
    }
    float mx = fmaxf(v[0], v[1]);
    for (int off = 32; off >= 1; off >>= 1) mx = fmaxf(mx, __shfl_xor(mx, off));
    if ((tid & 63) == 0) redw[tid >> 6] = mx;
    __syncthreads();
    mx = fmaxf(fmaxf(redw[0], redw[1]), fmaxf(redw[2], redw[3]));
    __syncthreads();
    v[0] = __expf(v[0] - mx);
    v[1] = __expf(v[1] - mx);
    float sm = v[0] + v[1];
    for (int off = 32; off >= 1; off >>= 1) sm += __shfl_xor(sm, off);
    if ((tid & 63) == 0) redw[tid >> 6] = sm;
    __syncthreads();
    sm = redw[0] + redw[1] + redw[2] + redw[3];
    float inv = 1.f / sm;
    Sb[n * NN + tid]       = v[0] * inv;
    Sb[n * NN + tid + 256] = v[1] * inv;
}

// ------------- per-node biases (f32) -------------
__global__ __launch_bounds__(256) void combine_kernel(const float* __restrict__ emb,
                                                      const float* __restrict__ pool,
                                                      float* __restrict__ out,
                                                      int per_n, int total) {
    for (int idx = blockIdx.x * 256 + threadIdx.x; idx < total; idx += gridDim.x * 256) {
        int n = idx / per_n;
        int rem = idx - n * per_n;
        float a = 0.f;
        #pragma unroll
        for (int d = 0; d < EMBD; d++) a += emb[n * EMBD + d] * pool[d * per_n + rem];
        out[idx] = a;
    }
}

// ------------- per-node weights -> fragment-ordered bf16 hi/lo -------------
__global__ __launch_bounds__(256) void combine_frag_kernel(const float* __restrict__ emb,
                                                           const float* __restrict__ pool,
                                                           unsigned short* __restrict__ outU,
                                                           int O, int OT) {
    size_t total = (size_t)NN * OT * 5 * 512;
    for (size_t idx = (size_t)blockIdx.x * 256 + threadIdx.x; idx < total;
         idx += (size_t)gridDim.x * 256) {
        int j = idx & 7;
        int l = (idx >> 3) & 63;
        size_t r = idx >> 9;
        int kc = (int)(r % 5); r /= 5;
        int ot = (int)(r % OT);
        int n  = (int)(r / OT);
        int kp = kc * 32 + ((l >> 4) << 3) + j;
        int o = ot * 16 + (l & 15);
        float v = 0.f;
        if (kp < 2 * CIN) {
            int kk = (kp >= CIN) ? 1 : 0;
            int i = kp - CIN * kk;
            const float* p = pool + ((size_t)(kk * CIN + i)) * O + o;
            #pragma unroll
            for (int d = 0; d < EMBD; d++)
                v += emb[n * EMBD + d] * p[(size_t)d * (2 * CIN) * O];
        }
        unsigned hi, lo;
        split_(v, hi, lo);
        size_t base = (((size_t)n * OT + ot) * 5 + kc) * 1024;
        outU[base + l * 8 + j] = (unsigned short)hi;
        outU[base + 512 + l * 8 + j] = (unsigned short)lo;
    }
}

// ------------- pack LSTM weights: bf16x2 pairs along k, layout [kk][520] -------------
__global__ __launch_bounds__(256) void pack_kernel(const float* __restrict__ w,
                                                   unsigned* __restrict__ wp, int K) {
    int idx = blockIdx.x * 256 + threadIdx.x;
    int KH = K >> 1;
    if (idx < KH * LG) {
        int kk = idx / LG, j = idx - kk * LG;
        wp[idx] = bf16rne_(w[j * K + 2 * kk]) | (bf16rne_(w[j * K + 2 * kk + 1]) << 16);
    }
}

__global__ __launch_bounds__(256) void zero_kernel(float* __restrict__ p, int n) {
    int i = blockIdx.x * 256 + threadIdx.x;
    if (i < n) p[i] = 0.f;
}

// ------------- layer-0 x-projection (f32 weights, all t parallel) -------------
__global__ __launch_bounds__(256) void lstm_xp0_kernel(const float* __restrict__ sr,
                                                       const float* __restrict__ Wih0,
                                                       const float* __restrict__ bih0,
                                                       const float* __restrict__ bhh0,
                                                       float* __restrict__ xp0) {
    const int b = blockIdx.x, t = blockIdx.y, tid = threadIdx.x;
    __shared__ float xs[64];
    if (tid < 64) xs[tid] = sr[(size_t)(b * 32 + t) * 64 + tid];
    __syncthreads();
    for (int s = 0; s < 3; s++) {
        if (s == 2 && tid >= 8) break;
        int j = (s == 2) ? (512 + tid) : (tid + s * 256);
        float a = bih0[j] + bhh0[j];
        #pragma unroll 8
        for (int k = 0; k < 64; k++) a += xs[k] * Wih0[(size_t)j * 64 + k];
        xp0[((size_t)b * 32 + t) * 520 + j] = a;
    }
}

// ------------- persistent LSTM role: one block per batch, appended to GRU dispatches -------------
// st layout per b (528 floats): [0,132) h0, [132,264) c0, [264,396) h2, [396,528) c2
__device__ __forceinline__ void lstm_role(int slot, int b, int tid,
    const float* __restrict__ xp0,
    const unsigned* __restrict__ whh0,   // [65][520] packed bf16 pairs
    const unsigned* __restrict__ wih1,   // [65][520]
    const unsigned* __restrict__ whh1,   // [65][520]
    const float* __restrict__ bih1, const float* __restrict__ bhh1,
    float* __restrict__ h1seq,           // [16][32][130]
    float* __restrict__ st,              // [16][528]
    float* __restrict__ h2last) {
    __shared__ float hL[132];
    __shared__ float cL[132];
    __shared__ float xL[132];
    __shared__ float gL[520];
    float* stb = st + (size_t)b * 528;

    if (slot < 16) {
        for (int i = tid; i < 132; i += 256) { hL[i] = stb[i]; cL[i] = stb[132 + i]; }
        __syncthreads();
        for (int ts = 0; ts < 2; ts++) {
            int t = slot * 2 + ts;
            const float* xpt = xp0 + ((size_t)b * 32 + t) * 520;
            for (int s = 0; s < 3; s++) {
                if (s == 2 && tid >= 8) break;
                int j = (s == 2) ? (512 + tid) : (tid + s * 256);
                float a0 = 0.f, a1 = 0.f, a2 = 0.f, a3 = 0.f;
                #pragma unroll
                for (int kk = 0; kk < 64; kk += 4) {
                    unsigned p0 = whh0[(kk + 0) * 520 + j];
                    unsigned p1 = whh0[(kk + 1) * 520 + j];
                    unsigned p2 = whh0[(kk + 2) * 520 + j];
                    unsigned p3 = whh0[(kk + 3) * 520 + j];
                    a0 += hL[2 * kk + 0] * bl_(p0) + hL[2 * kk + 1] * bh_(p0);
                    a1 += hL[2 * kk + 2] * bl_(p1) + hL[2 * kk + 3] * bh_(p1);
                    a2 += hL[2 * kk + 4] * bl_(p2) + hL[2 * kk + 5] * bh_(p2);
                    a3 += hL[2 * kk + 6] * bl_(p3) + hL[2 * kk + 7] * bh_(p3);
                }
                { unsigned p = whh0[64 * 520 + j]; a0 += hL[128] * bl_(p) + hL[129] * bh_(p); }
                gL[j] = xpt[j] + ((a0 + a1) + (a2 + a3));
            }
            __syncthreads();
            if (tid < 130) {
                float iv = sigmoidf_(gL[tid]);
                float fv = sigmoidf_(gL[130 + tid]);
                float gv = tanhf_(gL[260 + tid]);
                float ov = sigmoidf_(gL[390 + tid]);
                float cv = fv * cL[tid] + iv * gv;
                cL[tid] = cv;
                float hv = ov * tanhf_(cv);
                hL[tid] = hv;
                h1seq[((size_t)b * 32 + t) * 130 + tid] = hv;
            }
            __syncthreads();
        }
        for (int i = tid; i < 132; i += 256) { stb[i] = hL[i]; stb[132 + i] = cL[i]; }
    } else {
        int t = slot - 16;
        for (int i = tid; i < 132; i += 256) {
            hL[i] = stb[264 + i];
            cL[i] = stb[396 + i];
            xL[i] = (i < 130) ? h1seq[((size_t)b * 32 + t) * 130 + i] : 0.f;
        }
        __syncthreads();
        for (int s = 0; s < 3; s++) {
            if (s == 2 && tid >= 8) break;
            int j = (s == 2) ? (512 + tid) : (tid + s * 256);
            float a0 = 0.f, a1 = 0.f, a2 = 0.f, a3 = 0.f;
            #pragma unroll
            for (int kk = 0; kk < 64; kk += 2) {
                unsigned p0 = wih1[(kk + 0) * 520 + j];
                unsigned p1 = wih1[(kk + 1) * 520 + j];
                a0 += xL[2 * kk + 0] * bl_(p0) + xL[2 * kk + 1] * bh_(p0);
                a1 += xL[2 * kk + 2] * bl_(p1) + xL[2 * kk + 3] * bh_(p1);
                unsigned q0 = whh1[(kk + 0) * 520 + j];
                unsigned q1 = whh1[(kk + 1) * 520 + j];
                a2 += hL[2 * kk + 0] * bl_(q0) + hL[2 * kk + 1] * bh_(q0);
                a3 += hL[2 * kk + 2] * bl_(q1) + hL[2 * kk + 3] * bh_(q1);
            }
            { unsigned p = wih1[64 * 520 + j]; a0 += xL[128] * bl_(p) + xL[129] * bh_(p); }
            { unsigned q = whh1[64 * 520 + j]; a2 += hL[128] * bl_(q) + hL[129] * bh_(q); }
            gL[j] = bih1[j] + bhh1[j] + ((a0 + a1) + (a2 + a3));
        }
        __syncthreads();
        if (tid < 130) {
            float iv = sigmoidf_(gL[tid]);
            float fv = sigmoidf_(gL[130 + tid]);
            float gv = tanhf_(gL[260 + tid]);
            float ov = sigmoidf_(gL[390 + tid]);
            float cv = fv * cL[tid] + iv * gv;
            float hv = ov * tanhf_(cv);
            stb[264 + tid] = hv;
            stb[396 + tid] = cv;
            if (t == 31) h2last[(size_t)b * LH + tid] = hv;
        }
    }
}

// ------------- init frag-ordered bf16 hi/lo of X (t=0) -------------
__global__ __launch_bounds__(256) void xfrag_kernel(const float* __restrict__ ent,
                                                    const float* __restrict__ state,
                                                    unsigned short* __restrict__ Xf,
                                                    int t) {
    int idx = blockIdx.x * 256 + threadIdx.x;
    int l = idx & 63;
    int r = idx >> 6;
    int kc = r & 1; r >>= 1;
    int ct = r % 5; r /= 5;
    int q = r & 7;
    int b = r >> 3;
    const int c = ct * 16 + (l & 15);
    const int mbase = q * 64 + kc * 32 + ((l >> 4) & 3) * 8;
    union { unsigned short u[8]; short8 v; } hi8, lo8;
    #pragma unroll
    for (int j = 0; j < 8; j++) {
        int m = mbase + j;
        float v = 0.f;
        if (c < CIN) {
            v = (c < DINV) ? ent[((size_t)(b * TT + t) * NN + m) * DINV + c]
                           : state[((size_t)b * NN + m) * HH + (c - DINV)];
        }
        unsigned hi, lo;
        split_(v, hi, lo);
        hi8.u[j] = (unsigned short)hi;
        lo8.u[j] = (unsigned short)lo;
    }
    size_t base = ((((size_t)b * 8 + q) * 5 + ct) * 2 + kc) * 1024;
    *(short8*)(Xf + base + l * 8) = hi8.v;
    *(short8*)(Xf + base + 512 + l * 8) = lo8.v;
}

// ------------- spmm (1D grid: 512 work blocks + 16 lstm blocks) -------------
__global__ __launch_bounds__(256) void spmm_kernel(const float* __restrict__ Sb,
                                                   const float* __restrict__ mask,
                                                   const unsigned short* __restrict__ Xf,
                                                   float* __restrict__ out, int t, int slot,
                                                   const float* __restrict__ xp0,
                                                   const unsigned* __restrict__ whh0,
                                                   const unsigned* __restrict__ wih1,
                                                   const unsigned* __restrict__ whh1,
                                                   const float* __restrict__ bih1,
                                                   const float* __restrict__ bhh1,
                                                   float* __restrict__ h1seq,
                                                   float* __restrict__ lst,
                                                   float* __restrict__ h2last) {
    const int bid = blockIdx.x;
    const int tid = threadIdx.x;
    if (bid >= 512) {
        lstm_role(slot, bid - 512, tid, xp0, whh0, wih1, whh1, bih1, bhh1,
                  h1seq, lst, h2last);
        return;
    }
    const int lane = tid & 63;
    const int w = tid >> 6;
    const int n0 = (bid & 7) * 64;
    const int b = (bid >> 3) & 15;
    const int z = bid >> 7;
    float* __restrict__ outp = out + (size_t)z * PART;
    const float* __restrict__ mrow = mask + (size_t)(b * TT + t) * NN * NN;
    const int nrow = n0 + w * 16 + (lane & 15);
    const int mgrp = ((lane >> 4) & 3) * 8;

    f32x4 acc[5];
    #pragma unroll
    for (int ct = 0; ct < 5; ct++) acc[ct] = (f32x4){0.f, 0.f, 0.f, 0.f};

    #pragma unroll
    for (int r2 = 0; r2 < 2; r2++) {
        const int q = z * 2 + r2;
        #pragma unroll
        for (int kc = 0; kc < 2; kc++) {
            const int mstart = q * 64 + kc * 32 + mgrp;
            const float4* s4 = (const float4*)(Sb + (size_t)nrow * NN + mstart);
            const float4* m4 = (const float4*)(mrow + (size_t)nrow * NN + mstart);
            float4 sa = s4[0], sc = s4[1];
            float4 ma = m4[0], mc = m4[1];
            float pv[8] = {sa.x * ma.x, sa.y * ma.y, sa.z * ma.z, sa.w * ma.w,
                           sc.x * mc.x, sc.y * mc.y, sc.z * mc.z, sc.w * mc.w};
            union { unsigned short u[8]; short8 v; } ah, al;
            #pragma unroll
            for (int j = 0; j < 8; j++) {
                unsigned hi, lo;
                split_(pv[j], hi, lo);
                ah.u[j] = (unsigned short)hi;
                al.u[j] = (unsigned short)lo;
            }
            #pragma unroll
            for (int ct = 0; ct < 5; ct++) {
                size_t base = ((((size_t)b * 8 + q) * 5 + ct) * 2 + kc) << 10;
                short8 bh = *(const short8*)(Xf + base + lane * 8);
                short8 bl = *(const short8*)(Xf + base + 512 + lane * 8);
                acc[ct] = __builtin_amdgcn_mfma_f32_16x16x32_bf16(ah.v, bh, acc[ct], 0, 0, 0);
                acc[ct] = __builtin_amdgcn_mfma_f32_16x16x32_bf16(ah.v, bl, acc[ct], 0, 0, 0);
                acc[ct] = __builtin_amdgcn_mfma_f32_16x16x32_bf16(al.v, bh, acc[ct], 0, 0, 0);
            }
        }
    }
    const int col = lane & 15, rq = lane >> 4;
    #pragma unroll
    for (int ct = 0; ct < 5; ct++) {
        int c = ct * 16 + col;
        if (c < CIN) {
            #pragma unroll
            for (int reg = 0; reg < 4; reg++) {
                int n = n0 + w * 16 + rq * 4 + reg;
                outp[(size_t)b * NN * CIN + n * CIN + c] = acc[ct][reg];
            }
        }
    }
}

// ------------- gate via MFMA; writes cand-frags into Xf; +16 lstm blocks -------------
__global__ __launch_bounds__(256) void gate_mfma_kernel(const float* __restrict__ ent,
                                                        const float* __restrict__ state,
                                                        const float* __restrict__ xg1,
                                                        const unsigned short* __restrict__ WgF,
                                                        const float* __restrict__ bg,
                                                        float* __restrict__ cand,
                                                        float* __restrict__ rbuf,
                                                        unsigned short* __restrict__ Xf,
                                                        int t, int slot,
                                                        const float* __restrict__ xp0,
                                                        const unsigned* __restrict__ whh0,
                                                        const unsigned* __restrict__ wih1,
                                                        const unsigned* __restrict__ whh1,
                                                        const float* __restrict__ bih1,
                                                        const float* __restrict__ bhh1,
                                                        float* __restrict__ h1seq,
                                                        float* __restrict__ lst,
                                                        float* __restrict__ h2last) {
    __shared__ unsigned short A_h[16 * 168], A_l[16 * 168];
    const int n = blockIdx.x;
    const int tid = threadIdx.x;
    if (n >= NN) {
        lstm_role(slot, n - NN, tid, xp0, whh0, wih1, whh1, bih1, bhh1,
                  h1seq, lst, h2last);
        return;
    }
    const int lane = tid & 63;
    const int w = tid >> 6;
    for (int idx = tid; idx < 16 * 36; idx += 256) {
        int b = idx / 36, k = 132 + idx - b * 36;
        A_h[b * 168 + k] = 0; A_l[b * 168 + k] = 0;
    }
    for (int idx = tid; idx < 16 * 132; idx += 256) {
        int b = idx / 132, ip = idx - b * 132;
        float v;
        if (ip < CIN) {
            v = (ip < DINV) ? ent[((size_t)(b * TT + t) * NN + n) * DINV + ip]
                            : state[((size_t)b * NN + n) * HH + (ip - DINV)];
        } else {
            size_t g = (size_t)b * NN * CIN + n * CIN + (ip - CIN);
            v = xg1[g] + xg1[g + PART] + xg1[g + 2 * PART] + xg1[g + 3 * PART];
        }
        unsigned hi, lo;
        split_(v, hi, lo);
        A_h[b * 168 + ip] = (unsigned short)hi;
        A_l[b * 168 + ip] = (unsigned short)lo;
    }
    __syncthreads();

    f32x4 acc0 = {0.f, 0.f, 0.f, 0.f}, acc1 = {0.f, 0.f, 0.f, 0.f};
    const unsigned short* Wn = WgF + (size_t)n * (8 * 5 * 1024);
    #pragma unroll
    for (int kc = 0; kc < 5; kc++) {
        int aoff = (lane & 15) * 168 + kc * 32 + (lane >> 4) * 8;
        short8 ah = *(const short8*)&A_h[aoff];
        short8 al = *(const short8*)&A_l[aoff];
        const unsigned short* f0 = Wn + ((size_t)(w * 5) + kc) * 1024 + lane * 8;
        short8 bh = *(const short8*)f0;
        short8 bl = *(const short8*)(f0 + 512);
        acc0 = __builtin_amdgcn_mfma_f32_16x16x32_bf16(ah, bh, acc0, 0, 0, 0);
        acc0 = __builtin_amdgcn_mfma_f32_16x16x32_bf16(ah, bl, acc0, 0, 0, 0);
        acc0 = __builtin_amdgcn_mfma_f32_16x16x32_bf16(al, bh, acc0, 0, 0, 0);
        const unsigned short* f1 = Wn + ((size_t)((w + 4) * 5) + kc) * 1024 + lane * 8;
        short8 bh1 = *(const short8*)f1;
        short8 bl1 = *(const short8*)(f1 + 512);
        acc1 = __builtin_amdgcn_mfma_f32_16x16x32_bf16(ah, bh1, acc1, 0, 0, 0);
        acc1 = __builtin_amdgcn_mfma_f32_16x16x32_bf16(ah, bl1, acc1, 0, 0, 0);
        acc1 = __builtin_amdgcn_mfma_f32_16x16x32_bf16(al, bh1, acc1, 0, 0, 0);
    }
    const int col = lane & 15, rq = lane >> 4;
    const int q = n >> 6, kcn = (n >> 5) & 1, jn = n & 7;
    {
        int o = w * 16 + col;
        int c = o + DINV;
        int ct = c >> 4, cl = c & 15;
        int l = ((n >> 3) & 3) * 16 + cl;
        float bias = bg[n * 128 + o];
        #pragma unroll
        for (int reg = 0; reg < 4; reg++) {
            int b = rq * 4 + reg;
            float zr = sigmoidf_(acc0[reg] + bias);
            float val = zr * state[((size_t)b * NN + n) * HH + o];
            cand[(size_t)b * NN * CIN + n * CIN + c] = val;
            unsigned hi, lo;
            split_(val, hi, lo);
            size_t fb = ((((size_t)b * 8 + q) * 5 + ct) * 2 + kcn) << 10;
            Xf[fb + l * 8 + jn] = (unsigned short)hi;
            Xf[fb + 512 + l * 8 + jn] = (unsigned short)lo;
        }
    }
    {
        int o = (w + 4) * 16 + col;
        float bias = bg[n * 128 + o];
        #pragma unroll
        for (int reg = 0; reg < 4; reg++) {
            int b = rq * 4 + reg;
            float zr = sigmoidf_(acc1[reg] + bias);
            rbuf[((size_t)b * NN + n) * HH + (o - HH)] = zr;
        }
    }
    if (tid < 32) {
        int b = tid >> 1, i = tid & 1;
        cand[(size_t)b * NN * CIN + n * CIN + i] =
            ent[((size_t)(b * TT + t) * NN + n) * DINV + i];
    }
}

// ------------- update via MFMA; writes state + frags + ent_{t+1}; +16 lstm blocks -------------
__global__ __launch_bounds__(256) void update_mfma_kernel(const float* __restrict__ cand,
                                                          const float* __restrict__ xg2,
                                                          const unsigned short* __restrict__ WuF,
                                                          const float* __restrict__ bu,
                                                          const float* __restrict__ rbuf,
                                                          float* __restrict__ state,
                                                          unsigned short* __restrict__ Xf,
                                                          const float* __restrict__ ent,
                                                          int tnext, int slot,
                                                          const float* __restrict__ xp0,
                                                          const unsigned* __restrict__ whh0,
                                                          const unsigned* __restrict__ wih1,
                                                          const unsigned* __restrict__ whh1,
                                                          const float* __restrict__ bih1,
                                                          const float* __restrict__ bhh1,
                                                          float* __restrict__ h1seq,
                                                          float* __restrict__ lst,
                                                          float* __restrict__ h2last) {
    __shared__ unsigned short A_h[16 * 168], A_l[16 * 168];
    const int n = blockIdx.x;
    const int tid = threadIdx.x;
    if (n >= NN) {
        lstm_role(slot, n - NN, tid, xp0, whh0, wih1, whh1, bih1, bhh1,
                  h1seq, lst, h2last);
        return;
    }
    const int lane = tid & 63;
    const int w = tid >> 6;
    for (int idx = tid; idx < 16 * 36; idx += 256) {
        int b = idx / 36, k = 132 + idx - b * 36;
        A_h[b * 168 + k] = 0; A_l[b * 168 + k] = 0;
    }
    for (int idx = tid; idx < 16 * 132; idx += 256) {
        int b = idx / 132, ip = idx - b * 132;
        float v;
        if (ip < CIN) {
            v = cand[(size_t)b * NN * CIN + n * CIN + ip];
        } else {
            size_t g = (size_t)b * NN * CIN + n * CIN + (ip - CIN);
            v = xg2[g] + xg2[g + PART] + xg2[g + 2 * PART] + xg2[g + 3 * PART];
        }
        unsigned hi, lo;
        split_(v, hi, lo);
        A_h[b * 168 + ip] = (unsigned short)hi;
        A_l[b * 168 + ip] = (unsigned short)lo;
    }
    __syncthreads();

    f32x4 acc = {0.f, 0.f, 0.f, 0.f};
    const unsigned short* Wn = WuF + (size_t)n * (4 * 5 * 1024);
    #pragma unroll
    for (int kc = 0; kc < 5; kc++) {
        int aoff = (lane & 15) * 168 + kc * 32 + (lane >> 4) * 8;
        short8 ah = *(const short8*)&A_h[aoff];
        short8 al = *(const short8*)&A_l[aoff];
        const unsigned short* f0 = Wn + ((size_t)(w * 5) + kc) * 1024 + lane * 8;
        short8 bh = *(const short8*)f0;
        short8 bl = *(const short8*)(f0 + 512);
        acc = __builtin_amdgcn_mfma_f32_16x16x32_bf16(ah, bh, acc, 0, 0, 0);
        acc = __builtin_amdgcn_mfma_f32_16x16x32_bf16(ah, bl, acc, 0, 0, 0);
        acc = __builtin_amdgcn_mfma_f32_16x16x32_bf16(al, bh, acc, 0, 0, 0);
    }
    const int col = lane & 15, rq = lane >> 4;
    const int q = n >> 6, kcn = (n >> 5) & 1, jn = n & 7;
    int o = w * 16 + col;
    int c = o + DINV;
    int ct = c >> 4, cl = c & 15;
    int l = ((n >> 3) & 3) * 16 + cl;
    float bias = bu[n * HH + o];
    #pragma unroll
    for (int reg = 0; reg < 4; reg++) {
        int b = rq * 4 + reg;
        float hc = tanhf_(acc[reg] + bias);
        size_t g = ((size_t)b * NN + n) * HH + o;
        float rr = rbuf[g];
        float ns = rr * state[g] + (1.f - rr) * hc;
        state[g] = ns;
        unsigned hi, lo;
        split_(ns, hi, lo);
        size_t fb = ((((size_t)b * 8 + q) * 5 + ct) * 2 + kcn) << 10;
        Xf[fb + l * 8 + jn] = (unsigned short)hi;
        Xf[fb + 512 + l * 8 + jn] = (unsigned short)lo;
    }
    if (w == 0 && col < DINV && tnext < TT) {
        int le = ((n >> 3) & 3) * 16 + col;
        #pragma unroll
        for (int reg = 0; reg < 4; reg++) {
            int b = rq * 4 + reg;
            float v = ent[((size_t)(b * TT + tnext) * NN + n) * DINV + col];
            unsigned hi, lo;
            split_(v, hi, lo);
            size_t fb = ((((size_t)b * 8 + q) * 5 + 0) * 2 + kcn) << 10;
            Xf[fb + le * 8 + jn] = (unsigned short)hi;
            Xf[fb + 512 + le * 8 + jn] = (unsigned short)lo;
        }
    }
}

// ------------- final -------------
__global__ __launch_bounds__(256) void final_kernel(const float* __restrict__ state,
                                                    const float* __restrict__ h2last,
                                                    const float* __restrict__ fcW,
                                                    const float* __restrict__ fcb,
                                                    float* __restrict__ out) {
    const int b = blockIdx.x;
    const int tid = threadIdx.x;
    __shared__ float feat[LH + HH];
    __shared__ float red[4][HH];
    const int hh = tid & 63, q = tid >> 6;
    float mx = -INFINITY;
    for (int n = q * 128; n < q * 128 + 128; n++)
        mx = fmaxf(mx, state[((size_t)b * NN + n) * HH + hh]);
    red[q][hh] = mx;
    if (tid >= 64 && tid < 64 + LH)
        feat[tid - 64] = h2last[(size_t)b * LH + (tid - 64)];
    __syncthreads();
    if (tid < HH)
        feat[LH + tid] = fmaxf(fmaxf(red[0][tid], red[1][tid]), fmaxf(red[2][tid], red[3][tid]));
    __syncthreads();
    if (tid < 24) {
        float a = fcb[tid];
        for (int k = 0; k < LH + HH; k++) a += feat[k] * fcW[tid * (LH + HH) + k];
        out[b * 24 + tid] = sigmoidf_(a);
    }
}

extern "C" void kernel_launch(void* const* d_in, const int* in_sizes, int n_in,
                              void* d_out, int out_size, void* d_ws, size_t ws_size,
                              hipStream_t stream) {
    const float* ent  = (const float*)d_in[0];
    const float* mask = (const float*)d_in[1];
    const float* sr   = (const float*)d_in[2];
    const float* emb  = (const float*)d_in[3];
    const float* gW   = (const float*)d_in[4];
    const float* gb   = (const float*)d_in[5];
    const float* uW   = (const float*)d_in[6];
    const float* ub   = (const float*)d_in[7];
    const float* Wih0 = (const float*)d_in[8];
    const float* Whh0 = (const float*)d_in[9];
    const float* bih0 = (const float*)d_in[10];
    const float* bhh0 = (const float*)d_in[11];
    const float* Wih1 = (const float*)d_in[12];
    const float* Whh1 = (const float*)d_in[13];
    const float* bih1 = (const float*)d_in[14];
    const float* bhh1 = (const float*)d_in[15];
    const float* fcW  = (const float*)d_in[16];
    const float* fcb  = (const float*)d_in[17];
    float* out = (float*)d_out;
    float* ws = (float*)d_ws;

    size_t off = 0;
    float* Sb     = ws + off; off += (size_t)NN * NN;
    unsigned short* WgF = (unsigned short*)(ws + off); off += (size_t)NN * 8 * 5 * 512;
    unsigned short* WuF = (unsigned short*)(ws + off); off += (size_t)NN * 4 * 5 * 512;
    float* bgc    = ws + off; off += (size_t)NN * 128;
    float* buc    = ws + off; off += (size_t)NN * HH;
    float* state  = ws + off; off += (size_t)BB * NN * HH;
    float* xgP    = ws + off; off += 4 * PART;
    float* cand   = ws + off; off += PART;
    float* rbuf   = ws + off; off += (size_t)BB * NN * HH;
    float* h2last = ws + off; off += (size_t)BB * LH;
    unsigned short* Xf = (unsigned short*)(ws + off); off += (size_t)BB * 8 * 5 * 2 * 512;
    unsigned* wp_hh0 = (unsigned*)(ws + off); off += 65 * LG;
    unsigned* wp_ih1 = (unsigned*)(ws + off); off += 65 * LG;
    unsigned* wp_hh1 = (unsigned*)(ws + off); off += 65 * LG;
    float* xp0    = ws + off; off += (size_t)BB * 32 * 520;
    float* h1seq  = ws + off; off += (size_t)BB * 32 * 130;
    float* lst    = ws + off; off += (size_t)BB * 528;

    // ---- one-time precompute ----
    sbase_kernel<<<NN, 256, 0, stream>>>(emb, Sb);
    combine_frag_kernel<<<20480, 256, 0, stream>>>(emb, gW, WgF, 128, 8);
    combine_frag_kernel<<<20480, 256, 0, stream>>>(emb, uW, WuF, 64, 4);
    combine_kernel<<<256, 256, 0, stream>>>(emb, gb, bgc, 128, NN * 128);
    combine_kernel<<<128, 256, 0, stream>>>(emb, ub, buc, HH, NN * HH);
    pack_kernel<<<(65 * LG + 255) / 256, 256, 0, stream>>>(Whh0, wp_hh0, 130);
    pack_kernel<<<(65 * LG + 255) / 256, 256, 0, stream>>>(Wih1, wp_ih1, 130);
    pack_kernel<<<(65 * LG + 255) / 256, 256, 0, stream>>>(Whh1, wp_hh1, 130);
    zero_kernel<<<(BB * NN * HH + 255) / 256, 256, 0, stream>>>(state, BB * NN * HH);
    zero_kernel<<<(BB * 528 + 255) / 256, 256, 0, stream>>>(lst, BB * 528);
    xfrag_kernel<<<320, 256, 0, stream>>>(ent, state, Xf, 0);
    lstm_xp0_kernel<<<dim3(BB, 32), 256, 0, stream>>>(sr, Wih0, bih0, bhh0, xp0);

    // ---- GRU over 12 timesteps; LSTM rides along in +16 blocks (48 slots) ----
    for (int t = 0; t < TT; t++) {
        spmm_kernel<<<528, 256, 0, stream>>>(Sb, mask, Xf, xgP, t, 4 * t + 0,
            xp0, wp_hh0, wp_ih1, wp_hh1, bih1, bhh1, h1seq, lst, h2last);
        gate_mfma_kernel<<<NN + 16, 256, 0, stream>>>(ent, state, xgP, WgF, bgc, cand, rbuf, Xf,
            t, 4 * t + 1, xp0, wp_hh0, wp_ih1, wp_hh1, bih1, bhh1, h1seq, lst, h2last);
        spmm_kernel<<<528, 256, 0, stream>>>(Sb, mask, Xf, xgP, t, 4 * t + 2,
            xp0, wp_hh0, wp_ih1, wp_hh1, bih1, bhh1, h1seq, lst, h2last);
        update_mfma_kernel<<<NN + 16, 256, 0, stream>>>(cand, xgP, WuF, buc, rbuf, state, Xf,
            ent, t + 1, 4 * t + 3, xp0, wp_hh0, wp_ih1, wp_hh1, bih1, bhh1, h1seq, lst, h2last);
    }

    // ---- final ----
    final_kernel<<<BB, 256, 0, stream>>>(state, h2last, fcW, fcb, out);
}

// Round 10
// 1141.550 us; speedup vs baseline: 2.2401x; 2.2401x over previous
//
#include <hip/hip_runtime.h>
#include <math.h>

#define NN 512
#define EMBD 10
#define HH 64
#define DINV 2
#define CIN 66
#define TT 12
#define BB 16
#define LH 130
#define LG 520
#define PART ((size_t)BB * NN * CIN)

typedef __attribute__((ext_vector_type(8))) short short8;
typedef __attribute__((ext_vector_type(4))) float f32x4;

__device__ __forceinline__ float sigmoidf_(float x) { return 1.f / (1.f + __expf(-x)); }
__device__ __forceinline__ float tanhf_(float x)    { return 1.f - 2.f / (1.f + __expf(2.f * x)); }
__device__ __forceinline__ float bl_(unsigned p) { return __uint_as_float(p << 16); }
__device__ __forceinline__ float bh_(unsigned p) { return __uint_as_float(p & 0xffff0000u); }
__device__ __forceinline__ unsigned bf16rne_(float f) {
    unsigned u = __float_as_uint(f);
    u += 0x7fff + ((u >> 16) & 1);
    return u >> 16;
}
__device__ __forceinline__ void split_(float v, unsigned& hi, unsigned& lo) {
    hi = bf16rne_(v);
    float hif = __uint_as_float(hi << 16);
    lo = bf16rne_(v - hif);
}

// ---------------- S_base = softmax(relu(emb @ emb^T)) ----------------
__global__ __launch_bounds__(256) void sbase_kernel(const float* __restrict__ emb,
                                                    float* __restrict__ Sb) {
    const int n = blockIdx.x;
    const int tid = threadIdx.x;
    __shared__ float en[EMBD];
    __shared__ float redw[4];
    if (tid < EMBD) en[tid] = emb[n * EMBD + tid];
    __syncthreads();
    float v[2];
    #pragma unroll
    for (int q = 0; q < 2; q++) {
        int m = tid + q * 256;
        float s = 0.f;
        #pragma unroll
        for (int d = 0; d < EMBD; d++) s += en[d] * emb[m * EMBD + d];
        v[q] = fmaxf(s, 0.f);
    }
    float mx = fmaxf(v[0], v[1]);
    for (int off = 32; off >= 1; off >>= 1) mx = fmaxf(mx, __shfl_xor(mx, off));
    if ((tid & 63) == 0) redw[tid >> 6] = mx;
    __syncthreads();
    mx = fmaxf(fmaxf(redw[0], redw[1]), fmaxf(redw[2], redw[3]));
    __syncthreads();
    v[0] = __expf(v[0] - mx);
    v[1] = __expf(v[1] - mx);
    float sm = v[0] + v[1];
    for (int off = 32; off >= 1; off >>= 1) sm += __shfl_xor(sm, off);
    if ((tid & 63) == 0) redw[tid >> 6] = sm;
    __syncthreads();
    sm = redw[0] + redw[1] + redw[2] + redw[3];
    float inv = 1.f / sm;
    Sb[n * NN + tid]       = v[0] * inv;
    Sb[n * NN + tid + 256] = v[1] * inv;
}

// ------------- per-node biases (f32) -------------
__global__ __launch_bounds__(256) void combine_kernel(const float* __restrict__ emb,
                                                      const float* __restrict__ pool,
                                                      float* __restrict__ out,
                                                      int per_n, int total) {
    for (int idx = blockIdx.x * 256 + threadIdx.x; idx < total; idx += gridDim.x * 256) {
        int n = idx / per_n;
        int rem = idx - n * per_n;
        float a = 0.f;
        #pragma unroll
        for (int d = 0; d < EMBD; d++) a += emb[n * EMBD + d] * pool[d * per_n + rem];
        out[idx] = a;
    }
}

// ------------- per-node weights -> fragment-ordered bf16 hi/lo -------------
__global__ __launch_bounds__(256) void combine_frag_kernel(const float* __restrict__ emb,
                                                           const float* __restrict__ pool,
                                                           unsigned short* __restrict__ outU,
                                                           int O, int OT) {
    size_t total = (size_t)NN * OT * 5 * 512;
    for (size_t idx = (size_t)blockIdx.x * 256 + threadIdx.x; idx < total;
         idx += (size_t)gridDim.x * 256) {
        int j = idx & 7;
        int l = (idx >> 3) & 63;
        size_t r = idx >> 9;
        int kc = (int)(r % 5); r /= 5;
        int ot = (int)(r % OT);
        int n  = (int)(r / OT);
        int kp = kc * 32 + ((l >> 4) << 3) + j;
        int o = ot * 16 + (l & 15);
        float v = 0.f;
        if (kp < 2 * CIN) {
            int kk = (kp >= CIN) ? 1 : 0;
            int i = kp - CIN * kk;
            const float* p = pool + ((size_t)(kk * CIN + i)) * O + o;
            #pragma unroll
            for (int d = 0; d < EMBD; d++)
                v += emb[n * EMBD + d] * p[(size_t)d * (2 * CIN) * O];
        }
        unsigned hi, lo;
        split_(v, hi, lo);
        size_t base = (((size_t)n * OT + ot) * 5 + kc) * 1024;
        outU[base + l * 8 + j] = (unsigned short)hi;
        outU[base + 512 + l * 8 + j] = (unsigned short)lo;
    }
}

// ------------- pack LSTM weights: bf16x2 pairs along k, col-major -------------
__global__ __launch_bounds__(256) void pack_kernel(const float* __restrict__ w,
                                                   unsigned* __restrict__ wp, int K) {
    int idx = blockIdx.x * 256 + threadIdx.x;
    int KH = K >> 1;
    if (idx < KH * LG) {
        int kk = idx / LG, j = idx - kk * LG;
        wp[idx] = bf16rne_(w[j * K + 2 * kk]) | (bf16rne_(w[j * K + 2 * kk + 1]) << 16);
    }
}

__global__ __launch_bounds__(256) void zero_kernel(float* __restrict__ p, int n) {
    int i = blockIdx.x * 256 + threadIdx.x;
    if (i < n) p[i] = 0.f;
}

// ------------- init frag-ordered bf16 hi/lo of X (t=0: ent_0 + zero state) -------------
__global__ __launch_bounds__(256) void xfrag_kernel(const float* __restrict__ ent,
                                                    const float* __restrict__ state,
                                                    unsigned short* __restrict__ Xf,
                                                    int t) {
    int idx = blockIdx.x * 256 + threadIdx.x;
    int l = idx & 63;
    int r = idx >> 6;
    int kc = r & 1; r >>= 1;
    int ct = r % 5; r /= 5;
    int q = r & 7;
    int b = r >> 3;
    const int c = ct * 16 + (l & 15);
    const int mbase = q * 64 + kc * 32 + ((l >> 4) & 3) * 8;
    union { unsigned short u[8]; short8 v; } hi8, lo8;
    #pragma unroll
    for (int j = 0; j < 8; j++) {
        int m = mbase + j;
        float v = 0.f;
        if (c < CIN) {
            v = (c < DINV) ? ent[((size_t)(b * TT + t) * NN + m) * DINV + c]
                           : state[((size_t)b * NN + m) * HH + (c - DINV)];
        }
        unsigned hi, lo;
        split_(v, hi, lo);
        hi8.u[j] = (unsigned short)hi;
        lo8.u[j] = (unsigned short)lo;
    }
    size_t base = ((((size_t)b * 8 + q) * 5 + ct) * 2 + kc) * 1024;
    *(short8*)(Xf + base + l * 8) = hi8.v;
    *(short8*)(Xf + base + 512 + l * 8) = lo8.v;
}

// ------------- spmm: no LDS, no barriers. grid (8 ntiles, 16 b, 4 K-quarters) -------------
__global__ __launch_bounds__(256) void spmm_kernel(const float* __restrict__ Sb,
                                                   const float* __restrict__ mask,
                                                   const unsigned short* __restrict__ Xf,
                                                   float* __restrict__ out, int t) {
    const int tid = threadIdx.x;
    const int lane = tid & 63;
    const int w = tid >> 6;
    const int n0 = blockIdx.x * 64;
    const int b = blockIdx.y;
    const int z = blockIdx.z;
    float* __restrict__ outp = out + (size_t)z * PART;
    const float* __restrict__ mrow = mask + (size_t)(b * TT + t) * NN * NN;
    const int nrow = n0 + w * 16 + (lane & 15);
    const int mgrp = ((lane >> 4) & 3) * 8;

    f32x4 acc[5];
    #pragma unroll
    for (int ct = 0; ct < 5; ct++) acc[ct] = (f32x4){0.f, 0.f, 0.f, 0.f};

    #pragma unroll
    for (int r2 = 0; r2 < 2; r2++) {
        const int q = z * 2 + r2;
        #pragma unroll
        for (int kc = 0; kc < 2; kc++) {
            const int mstart = q * 64 + kc * 32 + mgrp;
            const float4* s4 = (const float4*)(Sb + (size_t)nrow * NN + mstart);
            const float4* m4 = (const float4*)(mrow + (size_t)nrow * NN + mstart);
            float4 sa = s4[0], sc = s4[1];
            float4 ma = m4[0], mc = m4[1];
            float pv[8] = {sa.x * ma.x, sa.y * ma.y, sa.z * ma.z, sa.w * ma.w,
                           sc.x * mc.x, sc.y * mc.y, sc.z * mc.z, sc.w * mc.w};
            union { unsigned short u[8]; short8 v; } ah, al;
            #pragma unroll
            for (int j = 0; j < 8; j++) {
                unsigned hi, lo;
                split_(pv[j], hi, lo);
                ah.u[j] = (unsigned short)hi;
                al.u[j] = (unsigned short)lo;
            }
            #pragma unroll
            for (int ct = 0; ct < 5; ct++) {
                size_t base = ((((size_t)b * 8 + q) * 5 + ct) * 2 + kc) << 10;
                short8 bh = *(const short8*)(Xf + base + lane * 8);
                short8 bl = *(const short8*)(Xf + base + 512 + lane * 8);
                acc[ct] = __builtin_amdgcn_mfma_f32_16x16x32_bf16(ah.v, bh, acc[ct], 0, 0, 0);
                acc[ct] = __builtin_amdgcn_mfma_f32_16x16x32_bf16(ah.v, bl, acc[ct], 0, 0, 0);
                acc[ct] = __builtin_amdgcn_mfma_f32_16x16x32_bf16(al.v, bh, acc[ct], 0, 0, 0);
            }
        }
    }
    const int col = lane & 15, rq = lane >> 4;
    #pragma unroll
    for (int ct = 0; ct < 5; ct++) {
        int c = ct * 16 + col;
        if (c < CIN) {
            #pragma unroll
            for (int reg = 0; reg < 4; reg++) {
                int n = n0 + w * 16 + rq * 4 + reg;
                outp[(size_t)b * NN * CIN + n * CIN + c] = acc[ct][reg];
            }
        }
    }
}

// ------------- gate via MFMA; also writes cand-frags into Xf -------------
__global__ __launch_bounds__(256) void gate_mfma_kernel(const float* __restrict__ ent,
                                                        const float* __restrict__ state,
                                                        const float* __restrict__ xg1,
                                                        const unsigned short* __restrict__ WgF,
                                                        const float* __restrict__ bg,
                                                        float* __restrict__ cand,
                                                        float* __restrict__ rbuf,
                                                        unsigned short* __restrict__ Xf,
                                                        int t) {
    __shared__ unsigned short A_h[16 * 168], A_l[16 * 168];
    const int n = blockIdx.x;
    const int tid = threadIdx.x;
    const int lane = tid & 63;
    const int w = tid >> 6;
    for (int idx = tid; idx < 16 * 36; idx += 256) {
        int b = idx / 36, k = 132 + idx - b * 36;
        A_h[b * 168 + k] = 0; A_l[b * 168 + k] = 0;
    }
    for (int idx = tid; idx < 16 * 132; idx += 256) {
        int b = idx / 132, ip = idx - b * 132;
        float v;
        if (ip < CIN) {
            v = (ip < DINV) ? ent[((size_t)(b * TT + t) * NN + n) * DINV + ip]
                            : state[((size_t)b * NN + n) * HH + (ip - DINV)];
        } else {
            size_t g = (size_t)b * NN * CIN + n * CIN + (ip - CIN);
            v = xg1[g] + xg1[g + PART] + xg1[g + 2 * PART] + xg1[g + 3 * PART];
        }
        unsigned hi, lo;
        split_(v, hi, lo);
        A_h[b * 168 + ip] = (unsigned short)hi;
        A_l[b * 168 + ip] = (unsigned short)lo;
    }
    __syncthreads();

    f32x4 acc0 = {0.f, 0.f, 0.f, 0.f}, acc1 = {0.f, 0.f, 0.f, 0.f};
    const unsigned short* Wn = WgF + (size_t)n * (8 * 5 * 1024);
    #pragma unroll
    for (int kc = 0; kc < 5; kc++) {
        int aoff = (lane & 15) * 168 + kc * 32 + (lane >> 4) * 8;
        short8 ah = *(const short8*)&A_h[aoff];
        short8 al = *(const short8*)&A_l[aoff];
        const unsigned short* f0 = Wn + ((size_t)(w * 5) + kc) * 1024 + lane * 8;
        short8 bh = *(const short8*)f0;
        short8 bl = *(const short8*)(f0 + 512);
        acc0 = __builtin_amdgcn_mfma_f32_16x16x32_bf16(ah, bh, acc0, 0, 0, 0);
        acc0 = __builtin_amdgcn_mfma_f32_16x16x32_bf16(ah, bl, acc0, 0, 0, 0);
        acc0 = __builtin_amdgcn_mfma_f32_16x16x32_bf16(al, bh, acc0, 0, 0, 0);
        const unsigned short* f1 = Wn + ((size_t)((w + 4) * 5) + kc) * 1024 + lane * 8;
        short8 bh1 = *(const short8*)f1;
        short8 bl1 = *(const short8*)(f1 + 512);
        acc1 = __builtin_amdgcn_mfma_f32_16x16x32_bf16(ah, bh1, acc1, 0, 0, 0);
        acc1 = __builtin_amdgcn_mfma_f32_16x16x32_bf16(ah, bl1, acc1, 0, 0, 0);
        acc1 = __builtin_amdgcn_mfma_f32_16x16x32_bf16(al, bh1, acc1, 0, 0, 0);
    }
    const int col = lane & 15, rq = lane >> 4;
    const int q = n >> 6, kcn = (n >> 5) & 1, jn = n & 7;
    {
        int o = w * 16 + col;
        int c = o + DINV;
        int ct = c >> 4, cl = c & 15;
        int l = ((n >> 3) & 3) * 16 + cl;
        float bias = bg[n * 128 + o];
        #pragma unroll
        for (int reg = 0; reg < 4; reg++) {
            int b = rq * 4 + reg;
            float zr = sigmoidf_(acc0[reg] + bias);
            float val = zr * state[((size_t)b * NN + n) * HH + o];
            cand[(size_t)b * NN * CIN + n * CIN + c] = val;
            unsigned hi, lo;
            split_(val, hi, lo);
            size_t fb = ((((size_t)b * 8 + q) * 5 + ct) * 2 + kcn) << 10;
            Xf[fb + l * 8 + jn] = (unsigned short)hi;
            Xf[fb + 512 + l * 8 + jn] = (unsigned short)lo;
        }
    }
    {
        int o = (w + 4) * 16 + col;
        float bias = bg[n * 128 + o];
        #pragma unroll
        for (int reg = 0; reg < 4; reg++) {
            int b = rq * 4 + reg;
            float zr = sigmoidf_(acc1[reg] + bias);
            rbuf[((size_t)b * NN + n) * HH + (o - HH)] = zr;
        }
    }
    if (tid < 32) {
        int b = tid >> 1, i = tid & 1;
        cand[(size_t)b * NN * CIN + n * CIN + i] =
            ent[((size_t)(b * TT + t) * NN + n) * DINV + i];
    }
}

// ------------- update via MFMA; writes state + state-frags + ent_{t+1}-frags -------------
__global__ __launch_bounds__(256) void update_mfma_kernel(const float* __restrict__ cand,
                                                          const float* __restrict__ xg2,
                                                          const unsigned short* __restrict__ WuF,
                                                          const float* __restrict__ bu,
                                                          const float* __restrict__ rbuf,
                                                          float* __restrict__ state,
                                                          unsigned short* __restrict__ Xf,
                                                          const float* __restrict__ ent,
                                                          int tnext) {
    __shared__ unsigned short A_h[16 * 168], A_l[16 * 168];
    const int n = blockIdx.x;
    const int tid = threadIdx.x;
    const int lane = tid & 63;
    const int w = tid >> 6;
    for (int idx = tid; idx < 16 * 36; idx += 256) {
        int b = idx / 36, k = 132 + idx - b * 36;
        A_h[b * 168 + k] = 0; A_l[b * 168 + k] = 0;
    }
    for (int idx = tid; idx < 16 * 132; idx += 256) {
        int b = idx / 132, ip = idx - b * 132;
        float v;
        if (ip < CIN) {
            v = cand[(size_t)b * NN * CIN + n * CIN + ip];
        } else {
            size_t g = (size_t)b * NN * CIN + n * CIN + (ip - CIN);
            v = xg2[g] + xg2[g + PART] + xg2[g + 2 * PART] + xg2[g + 3 * PART];
        }
        unsigned hi, lo;
        split_(v, hi, lo);
        A_h[b * 168 + ip] = (unsigned short)hi;
        A_l[b * 168 + ip] = (unsigned short)lo;
    }
    __syncthreads();

    f32x4 acc = {0.f, 0.f, 0.f, 0.f};
    const unsigned short* Wn = WuF + (size_t)n * (4 * 5 * 1024);
    #pragma unroll
    for (int kc = 0; kc < 5; kc++) {
        int aoff = (lane & 15) * 168 + kc * 32 + (lane >> 4) * 8;
        short8 ah = *(const short8*)&A_h[aoff];
        short8 al = *(const short8*)&A_l[aoff];
        const unsigned short* f0 = Wn + ((size_t)(w * 5) + kc) * 1024 + lane * 8;
        short8 bh = *(const short8*)f0;
        short8 bl = *(const short8*)(f0 + 512);
        acc = __builtin_amdgcn_mfma_f32_16x16x32_bf16(ah, bh, acc, 0, 0, 0);
        acc = __builtin_amdgcn_mfma_f32_16x16x32_bf16(ah, bl, acc, 0, 0, 0);
        acc = __builtin_amdgcn_mfma_f32_16x16x32_bf16(al, bh, acc, 0, 0, 0);
    }
    const int col = lane & 15, rq = lane >> 4;
    const int q = n >> 6, kcn = (n >> 5) & 1, jn = n & 7;
    int o = w * 16 + col;
    int c = o + DINV;
    int ct = c >> 4, cl = c & 15;
    int l = ((n >> 3) & 3) * 16 + cl;
    float bias = bu[n * HH + o];
    #pragma unroll
    for (int reg = 0; reg < 4; reg++) {
        int b = rq * 4 + reg;
        float hc = tanhf_(acc[reg] + bias);
        size_t g = ((size_t)b * NN + n) * HH + o;
        float rr = rbuf[g];
        float ns = rr * state[g] + (1.f - rr) * hc;
        state[g] = ns;
        unsigned hi, lo;
        split_(ns, hi, lo);
        size_t fb = ((((size_t)b * 8 + q) * 5 + ct) * 2 + kcn) << 10;
        Xf[fb + l * 8 + jn] = (unsigned short)hi;
        Xf[fb + 512 + l * 8 + jn] = (unsigned short)lo;
    }
    if (w == 0 && col < DINV && tnext < TT) {
        int le = ((n >> 3) & 3) * 16 + col;
        #pragma unroll
        for (int reg = 0; reg < 4; reg++) {
            int b = rq * 4 + reg;
            float v = ent[((size_t)(b * TT + tnext) * NN + n) * DINV + col];
            unsigned hi, lo;
            split_(v, hi, lo);
            size_t fb = ((((size_t)b * 8 + q) * 5 + 0) * 2 + kcn) << 10;
            Xf[fb + le * 8 + jn] = (unsigned short)hi;
            Xf[fb + 512 + le * 8 + jn] = (unsigned short)lo;
        }
    }
}

// ------------- fused 2-layer LSTM: 16 blocks, 8 waves, weights in VGPR -------------
// launch_bounds (512,1): VGPR cap 256 (2 waves/SIMD x 256 = full pool) -> room for
// 4-accumulator ILP + load pipelining. Dep chains 130 -> ~32 FMA.
__global__ __launch_bounds__(512, 1) void lstm_fused_kernel(
    const float* __restrict__ sr,
    const unsigned* __restrict__ wp_ih0, const float* __restrict__ Wih0,
    const float* __restrict__ bih0, const float* __restrict__ bhh0,
    const unsigned* __restrict__ wp_hh0, const float* __restrict__ Whh0,
    const unsigned* __restrict__ wp_ih1, const float* __restrict__ Wih1,
    const float* __restrict__ bih1, const float* __restrict__ bhh1,
    const unsigned* __restrict__ wp_hh1, const float* __restrict__ Whh1,
    float* __restrict__ h2last) {
    const int b = blockIdx.x;
    const int tid = threadIdx.x;
    const int lane = tid & 63;
    const int wv = tid >> 6;
    __shared__ __align__(16) float xp[32 * 520];
    __shared__ __align__(16) float h1s[32 * 132];
    __shared__ __align__(16) float xs[32 * 64];
    __shared__ __align__(16) float hS[132], cS[132];
    __shared__ float gS[520];
    __shared__ float WeX[130 * 8];
    unsigned wpk[65];

    for (int l = tid; l < 32 * 64; l += 512) xs[l] = sr[(size_t)b * 2048 + l];
    #pragma unroll
    for (int kk = 0; kk < 32; kk++) wpk[kk] = wp_ih0[kk * 520 + tid];
    for (int l = tid; l < 64 * 8; l += 512) { int k = l >> 3, je = l & 7; WeX[l] = Wih0[(512 + je) * 64 + k]; }
    __syncthreads();
    {
        float bias = bih0[tid] + bhh0[tid];
        for (int t = 0; t < 32; t++) {
            const float4* x4 = (const float4*)&xs[t * 64];
            float a0 = 0.f, a1 = 0.f, a2 = 0.f, a3 = 0.f;
            #pragma unroll
            for (int q = 0; q < 16; q += 4) {
                float4 v0 = x4[q + 0]; unsigned p0 = wpk[2 * q + 0], p1 = wpk[2 * q + 1];
                float4 v1 = x4[q + 1]; unsigned p2 = wpk[2 * q + 2], p3 = wpk[2 * q + 3];
                float4 v2 = x4[q + 2]; unsigned p4 = wpk[2 * q + 4], p5 = wpk[2 * q + 5];
                float4 v3 = x4[q + 3]; unsigned p6 = wpk[2 * q + 6], p7 = wpk[2 * q + 7];
                a0 += v0.x * bl_(p0) + v0.y * bh_(p0) + v0.z * bl_(p1) + v0.w * bh_(p1);
                a1 += v1.x * bl_(p2) + v1.y * bh_(p2) + v1.z * bl_(p3) + v1.w * bh_(p3);
                a2 += v2.x * bl_(p4) + v2.y * bh_(p4) + v2.z * bl_(p5) + v2.w * bh_(p5);
                a3 += v3.x * bl_(p6) + v3.y * bh_(p6) + v3.z * bl_(p7) + v3.w * bh_(p7);
            }
            xp[t * 520 + tid] = bias + ((a0 + a1) + (a2 + a3));
        }
        if (tid < 256) {
            int je = tid & 7, t = tid >> 3;
            float a = bih0[512 + je] + bhh0[512 + je];
            for (int k = 0; k < 64; k++) a += xs[t * 64 + k] * WeX[k * 8 + je];
            xp[t * 520 + 512 + je] = a;
        }
    }
    __syncthreads();

    #pragma unroll
    for (int kk = 0; kk < 65; kk++) wpk[kk] = wp_hh0[kk * 520 + tid];
    for (int l = tid; l < 130 * 8; l += 512) { int k = l >> 3, je = l & 7; WeX[l] = Whh0[(512 + je) * 130 + k]; }
    for (int l = tid; l < 132; l += 512) { hS[l] = 0.f; cS[l] = 0.f; }
    __syncthreads();
    {
        float we0 = WeX[lane * 8 + wv];
        float we1 = WeX[(lane + 64) * 8 + wv];
        float we2 = (lane < 2) ? WeX[(lane + 128) * 8 + wv] : 0.f;
        for (int t = 0; t < 32; t++) {
            const float4* h4 = (const float4*)hS;
            float a0 = 0.f, a1 = 0.f, a2 = 0.f, a3 = 0.f;
            #pragma unroll
            for (int q = 0; q < 32; q += 4) {
                float4 v0 = h4[q + 0]; unsigned p0 = wpk[2 * q + 0], p1 = wpk[2 * q + 1];
                float4 v1 = h4[q + 1]; unsigned p2 = wpk[2 * q + 2], p3 = wpk[2 * q + 3];
                float4 v2 = h4[q + 2]; unsigned p4 = wpk[2 * q + 4], p5 = wpk[2 * q + 5];
                float4 v3 = h4[q + 3]; unsigned p6 = wpk[2 * q + 6], p7 = wpk[2 * q + 7];
                a0 += v0.x * bl_(p0) + v0.y * bh_(p0) + v0.z * bl_(p1) + v0.w * bh_(p1);
                a1 += v1.x * bl_(p2) + v1.y * bh_(p2) + v1.z * bl_(p3) + v1.w * bh_(p3);
                a2 += v2.x * bl_(p4) + v2.y * bh_(p4) + v2.z * bl_(p5) + v2.w * bh_(p5);
                a3 += v3.x * bl_(p6) + v3.y * bh_(p6) + v3.z * bl_(p7) + v3.w * bh_(p7);
            }
            { unsigned pc = wpk[64]; a0 += hS[128] * bl_(pc) + hS[129] * bh_(pc); }
            gS[tid] = xp[t * 520 + tid] + ((a0 + a1) + (a2 + a3));
            float p = hS[lane] * we0 + hS[lane + 64] * we1;
            if (lane < 2) p += hS[lane + 128] * we2;
            #pragma unroll
            for (int off = 32; off >= 1; off >>= 1) p += __shfl_xor(p, off);
            if (lane == 0) gS[512 + wv] = xp[t * 520 + 512 + wv] + p;
            __syncthreads();
            if (tid < 130) {
                float iv = sigmoidf_(gS[tid]);
                float fv = sigmoidf_(gS[130 + tid]);
                float gv = tanhf_(gS[260 + tid]);
                float ov = sigmoidf_(gS[390 + tid]);
                float cv = fv * cS[tid] + iv * gv;
                cS[tid] = cv;
                float hv = ov * tanhf_(cv);
                hS[tid] = hv;
                h1s[t * 132 + tid] = hv;
            }
            __syncthreads();
        }
    }

    #pragma unroll
    for (int kk = 0; kk < 65; kk++) wpk[kk] = wp_ih1[kk * 520 + tid];
    for (int l = tid; l < 130 * 8; l += 512) { int k = l >> 3, je = l & 7; WeX[l] = Wih1[(512 + je) * 130 + k]; }
    __syncthreads();
    {
        float bias = bih1[tid] + bhh1[tid];
        for (int t = 0; t < 32; t++) {
            const float4* x4 = (const float4*)&h1s[t * 132];
            float a0 = 0.f, a1 = 0.f, a2 = 0.f, a3 = 0.f;
            #pragma unroll
            for (int q = 0; q < 32; q += 4) {
                float4 v0 = x4[q + 0]; unsigned p0 = wpk[2 * q + 0], p1 = wpk[2 * q + 1];
                float4 v1 = x4[q + 1]; unsigned p2 = wpk[2 * q + 2], p3 = wpk[2 * q + 3];
                float4 v2 = x4[q + 2]; unsigned p4 = wpk[2 * q + 4], p5 = wpk[2 * q + 5];
                float4 v3 = x4[q + 3]; unsigned p6 = wpk[2 * q + 6], p7 = wpk[2 * q + 7];
                a0 += v0.x * bl_(p0) + v0.y * bh_(p0) + v0.z * bl_(p1) + v0.w * bh_(p1);
                a1 += v1.x * bl_(p2) + v1.y * bh_(p2) + v1.z * bl_(p3) + v1.w * bh_(p3);
                a2 += v2.x * bl_(p4) + v2.y * bh_(p4) + v2.z * bl_(p5) + v2.w * bh_(p5);
                a3 += v3.x * bl_(p6) + v3.y * bh_(p6) + v3.z * bl_(p7) + v3.w * bh_(p7);
            }
            { unsigned pc = wpk[64]; a0 += h1s[t * 132 + 128] * bl_(pc) + h1s[t * 132 + 129] * bh_(pc); }
            xp[t * 520 + tid] = bias + ((a0 + a1) + (a2 + a3));
        }
        if (tid < 256) {
            int je = tid & 7, t = tid >> 3;
            float a = bih1[512 + je] + bhh1[512 + je];
            for (int k = 0; k < 130; k++) a += h1s[t * 132 + k] * WeX[k * 8 + je];
            xp[t * 520 + 512 + je] = a;
        }
    }
    __syncthreads();

    #pragma unroll
    for (int kk = 0; kk < 65; kk++) wpk[kk] = wp_hh1[kk * 520 + tid];
    for (int l = tid; l < 130 * 8; l += 512) { int k = l >> 3, je = l & 7; WeX[l] = Whh1[(512 + je) * 130 + k]; }
    for (int l = tid; l < 132; l += 512) { hS[l] = 0.f; cS[l] = 0.f; }
    __syncthreads();
    {
        float we0 = WeX[lane * 8 + wv];
        float we1 = WeX[(lane + 64) * 8 + wv];
        float we2 = (lane < 2) ? WeX[(lane + 128) * 8 + wv] : 0.f;
        for (int t = 0; t < 32; t++) {
            const float4* h4 = (const float4*)hS;
            float a0 = 0.f, a1 = 0.f, a2 = 0.f, a3 = 0.f;
            #pragma unroll
            for (int q = 0; q < 32; q += 4) {
                float4 v0 = h4[q + 0]; unsigned p0 = wpk[2 * q + 0], p1 = wpk[2 * q + 1];
                float4 v1 = h4[q + 1]; unsigned p2 = wpk[2 * q + 2], p3 = wpk[2 * q + 3];
                float4 v2 = h4[q + 2]; unsigned p4 = wpk[2 * q + 4], p5 = wpk[2 * q + 5];
                float4 v3 = h4[q + 3]; unsigned p6 = wpk[2 * q + 6], p7 = wpk[2 * q + 7];
                a0 += v0.x * bl_(p0) + v0.y * bh_(p0) + v0.z * bl_(p1) + v0.w * bh_(p1);
                a1 += v1.x * bl_(p2) + v1.y * bh_(p2) + v1.z * bl_(p3) + v1.w * bh_(p3);
                a2 += v2.x * bl_(p4) + v2.y * bh_(p4) + v2.z * bl_(p5) + v2.w * bh_(p5);
                a3 += v3.x * bl_(p6) + v3.y * bh_(p6) + v3.z * bl_(p7) + v3.w * bh_(p7);
            }
            { unsigned pc = wpk[64]; a0 += hS[128] * bl_(pc) + hS[129] * bh_(pc); }
            gS[tid] = xp[t * 520 + tid] + ((a0 + a1) + (a2 + a3));
            float p = hS[lane] * we0 + hS[lane + 64] * we1;
            if (lane < 2) p += hS[lane + 128] * we2;
            #pragma unroll
            for (int off = 32; off >= 1; off >>= 1) p += __shfl_xor(p, off);
            if (lane == 0) gS[512 + wv] = xp[t * 520 + 512 + wv] + p;
            __syncthreads();
            if (tid < 130) {
                float iv = sigmoidf_(gS[tid]);
                float fv = sigmoidf_(gS[130 + tid]);
                float gv = tanhf_(gS[260 + tid]);
                float ov = sigmoidf_(gS[390 + tid]);
                float cv = fv * cS[tid] + iv * gv;
                cS[tid] = cv;
                float hv = ov * tanhf_(cv);
                hS[tid] = hv;
                if (t == 31) h2last[(size_t)b * LH + tid] = hv;
            }
            __syncthreads();
        }
    }
}

// ------------- final -------------
__global__ __launch_bounds__(256) void final_kernel(const float* __restrict__ state,
                                                    const float* __restrict__ h2last,
                                                    const float* __restrict__ fcW,
                                                    const float* __restrict__ fcb,
                                                    float* __restrict__ out) {
    const int b = blockIdx.x;
    const int tid = threadIdx.x;
    __shared__ float feat[LH + HH];
    __shared__ float red[4][HH];
    const int hh = tid & 63, q = tid >> 6;
    float mx = -INFINITY;
    for (int n = q * 128; n < q * 128 + 128; n++)
        mx = fmaxf(mx, state[((size_t)b * NN + n) * HH + hh]);
    red[q][hh] = mx;
    if (tid >= 64 && tid < 64 + LH)
        feat[tid - 64] = h2last[(size_t)b * LH + (tid - 64)];
    __syncthreads();
    if (tid < HH)
        feat[LH + tid] = fmaxf(fmaxf(red[0][tid], red[1][tid]), fmaxf(red[2][tid], red[3][tid]));
    __syncthreads();
    if (tid < 24) {
        float a = fcb[tid];
        for (int k = 0; k < LH + HH; k++) a += feat[k] * fcW[tid * (LH + HH) + k];
        out[b * 24 + tid] = sigmoidf_(a);
    }
}

extern "C" void kernel_launch(void* const* d_in, const int* in_sizes, int n_in,
                              void* d_out, int out_size, void* d_ws, size_t ws_size,
                              hipStream_t stream) {
    const float* ent  = (const float*)d_in[0];
    const float* mask = (const float*)d_in[1];
    const float* sr   = (const float*)d_in[2];
    const float* emb  = (const float*)d_in[3];
    const float* gW   = (const float*)d_in[4];
    const float* gb   = (const float*)d_in[5];
    const float* uW   = (const float*)d_in[6];
    const float* ub   = (const float*)d_in[7];
    const float* Wih0 = (const float*)d_in[8];
    const float* Whh0 = (const float*)d_in[9];
    const float* bih0 = (const float*)d_in[10];
    const float* bhh0 = (const float*)d_in[11];
    const float* Wih1 = (const float*)d_in[12];
    const float* Whh1 = (const float*)d_in[13];
    const float* bih1 = (const float*)d_in[14];
    const float* bhh1 = (const float*)d_in[15];
    const float* fcW  = (const float*)d_in[16];
    const float* fcb  = (const float*)d_in[17];
    float* out = (float*)d_out;
    float* ws = (float*)d_ws;

    size_t off = 0;
    float* Sb     = ws + off; off += (size_t)NN * NN;
    unsigned short* WgF = (unsigned short*)(ws + off); off += (size_t)NN * 8 * 5 * 512;
    unsigned short* WuF = (unsigned short*)(ws + off); off += (size_t)NN * 4 * 5 * 512;
    float* bgc    = ws + off; off += (size_t)NN * 128;
    float* buc    = ws + off; off += (size_t)NN * HH;
    float* state  = ws + off; off += (size_t)BB * NN * HH;
    float* xgP    = ws + off; off += 4 * PART;
    float* cand   = ws + off; off += PART;
    float* rbuf   = ws + off; off += (size_t)BB * NN * HH;
    float* h2last = ws + off; off += (size_t)BB * LH;
    unsigned short* Xf = (unsigned short*)(ws + off); off += (size_t)BB * 8 * 5 * 2 * 512;
    unsigned* wp_ih0 = (unsigned*)(ws + off); off += 32 * LG;
    unsigned* wp_hh0 = (unsigned*)(ws + off); off += 65 * LG;
    unsigned* wp_ih1 = (unsigned*)(ws + off); off += 65 * LG;
    unsigned* wp_hh1 = (unsigned*)(ws + off); off += 65 * LG;

    // ---- one-time precompute ----
    sbase_kernel<<<NN, 256, 0, stream>>>(emb, Sb);
    combine_frag_kernel<<<20480, 256, 0, stream>>>(emb, gW, WgF, 128, 8);
    combine_frag_kernel<<<20480, 256, 0, stream>>>(emb, uW, WuF, 64, 4);
    combine_kernel<<<256, 256, 0, stream>>>(emb, gb, bgc, 128, NN * 128);
    combine_kernel<<<128, 256, 0, stream>>>(emb, ub, buc, HH, NN * HH);
    pack_kernel<<<(32 * LG + 255) / 256, 256, 0, stream>>>(Wih0, wp_ih0, 64);
    pack_kernel<<<(65 * LG + 255) / 256, 256, 0, stream>>>(Whh0, wp_hh0, 130);
    pack_kernel<<<(65 * LG + 255) / 256, 256, 0, stream>>>(Wih1, wp_ih1, 130);
    pack_kernel<<<(65 * LG + 255) / 256, 256, 0, stream>>>(Whh1, wp_hh1, 130);
    zero_kernel<<<(BB * NN * HH + 255) / 256, 256, 0, stream>>>(state, BB * NN * HH);
    xfrag_kernel<<<320, 256, 0, stream>>>(ent, state, Xf, 0);

    // ---- GRU over 12 timesteps (4 dispatches each) ----
    for (int t = 0; t < TT; t++) {
        spmm_kernel<<<dim3(8, BB, 4), 256, 0, stream>>>(Sb, mask, Xf, xgP, t);
        gate_mfma_kernel<<<NN, 256, 0, stream>>>(ent, state, xgP, WgF, bgc, cand, rbuf, Xf, t);
        spmm_kernel<<<dim3(8, BB, 4), 256, 0, stream>>>(Sb, mask, Xf, xgP, t);
        update_mfma_kernel<<<NN, 256, 0, stream>>>(cand, xgP, WuF, buc, rbuf, state, Xf, ent, t + 1);
    }

    // ---- fused LSTM stack ----
    lstm_fused_kernel<<<BB, 512, 0, stream>>>(sr, wp_ih0, Wih0, bih0, bhh0, wp_hh0, Whh0,
                                              wp_ih1, Wih1, bih1, bhh1, wp_hh1, Whh1, h2last);

    // ---- final ----
    final_kernel<<<BB, 256, 0, stream>>>(state, h2last, fcW, fcb, out);
}

// Round 11
// 988.871 us; speedup vs baseline: 2.5860x; 1.1544x over previous
//
#include <hip/hip_runtime.h>
#include <math.h>

#define NN 512
#define EMBD 10
#define HH 64
#define DINV 2
#define CIN 66
#define TT 12
#define BB 16
#define LH 130
#define LG 520
#define PART ((size_t)BB * NN * CIN)

typedef __attribute__((ext_vector_type(8))) short short8;
typedef __attribute__((ext_vector_type(4))) float f32x4;
typedef __attribute__((ext_vector_type(2))) _Float16 h2v;

__device__ __forceinline__ float sigmoidf_(float x) { return 1.f / (1.f + __expf(-x)); }
__device__ __forceinline__ float tanhf_(float x)    { return 1.f - 2.f / (1.f + __expf(2.f * x)); }
__device__ __forceinline__ unsigned bf16rne_(float f) {
    unsigned u = __float_as_uint(f);
    u += 0x7fff + ((u >> 16) & 1);
    return u >> 16;
}
__device__ __forceinline__ void split_(float v, unsigned& hi, unsigned& lo) {
    hi = bf16rne_(v);
    float hif = __uint_as_float(hi << 16);
    lo = bf16rne_(v - hif);
}
// ---- f16 pair helpers (LSTM) ----
__device__ __forceinline__ unsigned pkh_(float a, float b) {
    _Float16 ha = (_Float16)a, hb = (_Float16)b;
    return (unsigned)__builtin_bit_cast(unsigned short, ha) |
           ((unsigned)__builtin_bit_cast(unsigned short, hb) << 16);
}
__device__ __forceinline__ float fdot2_(unsigned h, unsigned w, float c) {
#if __has_builtin(__builtin_amdgcn_fdot2)
    return __builtin_amdgcn_fdot2(__builtin_bit_cast(h2v, h), __builtin_bit_cast(h2v, w), c, false);
#else
    h2v H = __builtin_bit_cast(h2v, h), W = __builtin_bit_cast(h2v, w);
    return c + (float)H[0] * (float)W[0] + (float)H[1] * (float)W[1];
#endif
}
__device__ __forceinline__ float plo_(unsigned u) { return (float)__builtin_bit_cast(h2v, u)[0]; }
__device__ __forceinline__ float phi_(unsigned u) { return (float)__builtin_bit_cast(h2v, u)[1]; }

// ---------------- S_base = softmax(relu(emb @ emb^T)) ----------------
__global__ __launch_bounds__(256) void sbase_kernel(const float* __restrict__ emb,
                                                    float* __restrict__ Sb) {
    const int n = blockIdx.x;
    const int tid = threadIdx.x;
    __shared__ float en[EMBD];
    __shared__ float redw[4];
    if (tid < EMBD) en[tid] = emb[n * EMBD + tid];
    __syncthreads();
    float v[2];
    #pragma unroll
    for (int q = 0; q < 2; q++) {
        int m = tid + q * 256;
        float s = 0.f;
        #pragma unroll
        for (int d = 0; d < EMBD; d++) s += en[d] * emb[m * EMBD + d];
        v[q] = fmaxf(s, 0.f);
    }
    float mx = fmaxf(v[0], v[1]);
    for (int off = 32; off >= 1; off >>= 1) mx = fmaxf(mx, __shfl_xor(mx, off));
    if ((tid & 63) == 0) redw[tid >> 6] = mx;
    __syncthreads();
    mx = fmaxf(fmaxf(redw[0], redw[1]), fmaxf(redw[2], redw[3]));
    __syncthreads();
    v[0] = __expf(v[0] - mx);
    v[1] = __expf(v[1] - mx);
    float sm = v[0] + v[1];
    for (int off = 32; off >= 1; off >>= 1) sm += __shfl_xor(sm, off);
    if ((tid & 63) == 0) redw[tid >> 6] = sm;
    __syncthreads();
    sm = redw[0] + redw[1] + redw[2] + redw[3];
    float inv = 1.f / sm;
    Sb[n * NN + tid]       = v[0] * inv;
    Sb[n * NN + tid + 256] = v[1] * inv;
}

// ------------- per-node biases (f32) -------------
__global__ __launch_bounds__(256) void combine_kernel(const float* __restrict__ emb,
                                                      const float* __restrict__ pool,
                                                      float* __restrict__ out,
                                                      int per_n, int total) {
    for (int idx = blockIdx.x * 256 + threadIdx.x; idx < total; idx += gridDim.x * 256) {
        int n = idx / per_n;
        int rem = idx - n * per_n;
        float a = 0.f;
        #pragma unroll
        for (int d = 0; d < EMBD; d++) a += emb[n * EMBD + d] * pool[d * per_n + rem];
        out[idx] = a;
    }
}

// ------------- per-node weights -> fragment-ordered bf16 hi/lo -------------
__global__ __launch_bounds__(256) void combine_frag_kernel(const float* __restrict__ emb,
                                                           const float* __restrict__ pool,
                                                           unsigned short* __restrict__ outU,
                                                           int O, int OT) {
    size_t total = (size_t)NN * OT * 5 * 512;
    for (size_t idx = (size_t)blockIdx.x * 256 + threadIdx.x; idx < total;
         idx += (size_t)gridDim.x * 256) {
        int j = idx & 7;
        int l = (idx >> 3) & 63;
        size_t r = idx >> 9;
        int kc = (int)(r % 5); r /= 5;
        int ot = (int)(r % OT);
        int n  = (int)(r / OT);
        int kp = kc * 32 + ((l >> 4) << 3) + j;
        int o = ot * 16 + (l & 15);
        float v = 0.f;
        if (kp < 2 * CIN) {
            int kk = (kp >= CIN) ? 1 : 0;
            int i = kp - CIN * kk;
            const float* p = pool + ((size_t)(kk * CIN + i)) * O + o;
            #pragma unroll
            for (int d = 0; d < EMBD; d++)
                v += emb[n * EMBD + d] * p[(size_t)d * (2 * CIN) * O];
        }
        unsigned hi, lo;
        split_(v, hi, lo);
        size_t base = (((size_t)n * OT + ot) * 5 + kc) * 1024;
        outU[base + l * 8 + j] = (unsigned short)hi;
        outU[base + 512 + l * 8 + j] = (unsigned short)lo;
    }
}

// ------------- pack LSTM weights: f16x2 pairs along k, layout [kk][520] -------------
__global__ __launch_bounds__(256) void pack_kernel(const float* __restrict__ w,
                                                   unsigned* __restrict__ wp, int K) {
    int idx = blockIdx.x * 256 + threadIdx.x;
    int KH = K >> 1;
    if (idx < KH * LG) {
        int kk = idx / LG, j = idx - kk * LG;
        wp[idx] = pkh_(w[j * K + 2 * kk], w[j * K + 2 * kk + 1]);
    }
}

__global__ __launch_bounds__(256) void zero_kernel(float* __restrict__ p, int n) {
    int i = blockIdx.x * 256 + threadIdx.x;
    if (i < n) p[i] = 0.f;
}

// ------------- init frag-ordered bf16 hi/lo of X (t=0: ent_0 + zero state) -------------
__global__ __launch_bounds__(256) void xfrag_kernel(const float* __restrict__ ent,
                                                    const float* __restrict__ state,
                                                    unsigned short* __restrict__ Xf,
                                                    int t) {
    int idx = blockIdx.x * 256 + threadIdx.x;
    int l = idx & 63;
    int r = idx >> 6;
    int kc = r & 1; r >>= 1;
    int ct = r % 5; r /= 5;
    int q = r & 7;
    int b = r >> 3;
    const int c = ct * 16 + (l & 15);
    const int mbase = q * 64 + kc * 32 + ((l >> 4) & 3) * 8;
    union { unsigned short u[8]; short8 v; } hi8, lo8;
    #pragma unroll
    for (int j = 0; j < 8; j++) {
        int m = mbase + j;
        float v = 0.f;
        if (c < CIN) {
            v = (c < DINV) ? ent[((size_t)(b * TT + t) * NN + m) * DINV + c]
                           : state[((size_t)b * NN + m) * HH + (c - DINV)];
        }
        unsigned hi, lo;
        split_(v, hi, lo);
        hi8.u[j] = (unsigned short)hi;
        lo8.u[j] = (unsigned short)lo;
    }
    size_t base = ((((size_t)b * 8 + q) * 5 + ct) * 2 + kc) * 1024;
    *(short8*)(Xf + base + l * 8) = hi8.v;
    *(short8*)(Xf + base + 512 + l * 8) = lo8.v;
}

// ------------- spmm: no LDS, no barriers. grid (8 ntiles, 16 b, 4 K-quarters) -------------
__global__ __launch_bounds__(256) void spmm_kernel(const float* __restrict__ Sb,
                                                   const float* __restrict__ mask,
                                                   const unsigned short* __restrict__ Xf,
                                                   float* __restrict__ out, int t) {
    const int tid = threadIdx.x;
    const int lane = tid & 63;
    const int w = tid >> 6;
    const int n0 = blockIdx.x * 64;
    const int b = blockIdx.y;
    const int z = blockIdx.z;
    float* __restrict__ outp = out + (size_t)z * PART;
    const float* __restrict__ mrow = mask + (size_t)(b * TT + t) * NN * NN;
    const int nrow = n0 + w * 16 + (lane & 15);
    const int mgrp = ((lane >> 4) & 3) * 8;

    f32x4 acc[5];
    #pragma unroll
    for (int ct = 0; ct < 5; ct++) acc[ct] = (f32x4){0.f, 0.f, 0.f, 0.f};

    #pragma unroll
    for (int r2 = 0; r2 < 2; r2++) {
        const int q = z * 2 + r2;
        #pragma unroll
        for (int kc = 0; kc < 2; kc++) {
            const int mstart = q * 64 + kc * 32 + mgrp;
            const float4* s4 = (const float4*)(Sb + (size_t)nrow * NN + mstart);
            const float4* m4 = (const float4*)(mrow + (size_t)nrow * NN + mstart);
            float4 sa = s4[0], sc = s4[1];
            float4 ma = m4[0], mc = m4[1];
            float pv[8] = {sa.x * ma.x, sa.y * ma.y, sa.z * ma.z, sa.w * ma.w,
                           sc.x * mc.x, sc.y * mc.y, sc.z * mc.z, sc.w * mc.w};
            union { unsigned short u[8]; short8 v; } ah, al;
            #pragma unroll
            for (int j = 0; j < 8; j++) {
                unsigned hi, lo;
                split_(pv[j], hi, lo);
                ah.u[j] = (unsigned short)hi;
                al.u[j] = (unsigned short)lo;
            }
            #pragma unroll
            for (int ct = 0; ct < 5; ct++) {
                size_t base = ((((size_t)b * 8 + q) * 5 + ct) * 2 + kc) << 10;
                short8 bh = *(const short8*)(Xf + base + lane * 8);
                short8 bl = *(const short8*)(Xf + base + 512 + lane * 8);
                acc[ct] = __builtin_amdgcn_mfma_f32_16x16x32_bf16(ah.v, bh, acc[ct], 0, 0, 0);
                acc[ct] = __builtin_amdgcn_mfma_f32_16x16x32_bf16(ah.v, bl, acc[ct], 0, 0, 0);
                acc[ct] = __builtin_amdgcn_mfma_f32_16x16x32_bf16(al.v, bh, acc[ct], 0, 0, 0);
            }
        }
    }
    const int col = lane & 15, rq = lane >> 4;
    #pragma unroll
    for (int ct = 0; ct < 5; ct++) {
        int c = ct * 16 + col;
        if (c < CIN) {
            #pragma unroll
            for (int reg = 0; reg < 4; reg++) {
                int n = n0 + w * 16 + rq * 4 + reg;
                outp[(size_t)b * NN * CIN + n * CIN + c] = acc[ct][reg];
            }
        }
    }
}

// ------------- gate via MFMA; also writes cand-frags into Xf -------------
__global__ __launch_bounds__(256) void gate_mfma_kernel(const float* __restrict__ ent,
                                                        const float* __restrict__ state,
                                                        const float* __restrict__ xg1,
                                                        const unsigned short* __restrict__ WgF,
                                                        const float* __restrict__ bg,
                                                        float* __restrict__ cand,
                                                        float* __restrict__ rbuf,
                                                        unsigned short* __restrict__ Xf,
                                                        int t) {
    __shared__ unsigned short A_h[16 * 168], A_l[16 * 168];
    const int n = blockIdx.x;
    const int tid = threadIdx.x;
    const int lane = tid & 63;
    const int w = tid >> 6;
    for (int idx = tid; idx < 16 * 36; idx += 256) {
        int b = idx / 36, k = 132 + idx - b * 36;
        A_h[b * 168 + k] = 0; A_l[b * 168 + k] = 0;
    }
    for (int idx = tid; idx < 16 * 132; idx += 256) {
        int b = idx / 132, ip = idx - b * 132;
        float v;
        if (ip < CIN) {
            v = (ip < DINV) ? ent[((size_t)(b * TT + t) * NN + n) * DINV + ip]
                            : state[((size_t)b * NN + n) * HH + (ip - DINV)];
        } else {
            size_t g = (size_t)b * NN * CIN + n * CIN + (ip - CIN);
            v = xg1[g] + xg1[g + PART] + xg1[g + 2 * PART] + xg1[g + 3 * PART];
        }
        unsigned hi, lo;
        split_(v, hi, lo);
        A_h[b * 168 + ip] = (unsigned short)hi;
        A_l[b * 168 + ip] = (unsigned short)lo;
    }
    __syncthreads();

    f32x4 acc0 = {0.f, 0.f, 0.f, 0.f}, acc1 = {0.f, 0.f, 0.f, 0.f};
    const unsigned short* Wn = WgF + (size_t)n * (8 * 5 * 1024);
    #pragma unroll
    for (int kc = 0; kc < 5; kc++) {
        int aoff = (lane & 15) * 168 + kc * 32 + (lane >> 4) * 8;
        short8 ah = *(const short8*)&A_h[aoff];
        short8 al = *(const short8*)&A_l[aoff];
        const unsigned short* f0 = Wn + ((size_t)(w * 5) + kc) * 1024 + lane * 8;
        short8 bh = *(const short8*)f0;
        short8 bl = *(const short8*)(f0 + 512);
        acc0 = __builtin_amdgcn_mfma_f32_16x16x32_bf16(ah, bh, acc0, 0, 0, 0);
        acc0 = __builtin_amdgcn_mfma_f32_16x16x32_bf16(ah, bl, acc0, 0, 0, 0);
        acc0 = __builtin_amdgcn_mfma_f32_16x16x32_bf16(al, bh, acc0, 0, 0, 0);
        const unsigned short* f1 = Wn + ((size_t)((w + 4) * 5) + kc) * 1024 + lane * 8;
        short8 bh1 = *(const short8*)f1;
        short8 bl1 = *(const short8*)(f1 + 512);
        acc1 = __builtin_amdgcn_mfma_f32_16x16x32_bf16(ah, bh1, acc1, 0, 0, 0);
        acc1 = __builtin_amdgcn_mfma_f32_16x16x32_bf16(ah, bl1, acc1, 0, 0, 0);
        acc1 = __builtin_amdgcn_mfma_f32_16x16x32_bf16(al, bh1, acc1, 0, 0, 0);
    }
    const int col = lane & 15, rq = lane >> 4;
    const int q = n >> 6, kcn = (n >> 5) & 1, jn = n & 7;
    {
        int o = w * 16 + col;
        int c = o + DINV;
        int ct = c >> 4, cl = c & 15;
        int l = ((n >> 3) & 3) * 16 + cl;
        float bias = bg[n * 128 + o];
        #pragma unroll
        for (int reg = 0; reg < 4; reg++) {
            int b = rq * 4 + reg;
            float zr = sigmoidf_(acc0[reg] + bias);
            float val = zr * state[((size_t)b * NN + n) * HH + o];
            cand[(size_t)b * NN * CIN + n * CIN + c] = val;
            unsigned hi, lo;
            split_(val, hi, lo);
            size_t fb = ((((size_t)b * 8 + q) * 5 + ct) * 2 + kcn) << 10;
            Xf[fb + l * 8 + jn] = (unsigned short)hi;
            Xf[fb + 512 + l * 8 + jn] = (unsigned short)lo;
        }
    }
    {
        int o = (w + 4) * 16 + col;
        float bias = bg[n * 128 + o];
        #pragma unroll
        for (int reg = 0; reg < 4; reg++) {
            int b = rq * 4 + reg;
            float zr = sigmoidf_(acc1[reg] + bias);
            rbuf[((size_t)b * NN + n) * HH + (o - HH)] = zr;
        }
    }
    if (tid < 32) {
        int b = tid >> 1, i = tid & 1;
        cand[(size_t)b * NN * CIN + n * CIN + i] =
            ent[((size_t)(b * TT + t) * NN + n) * DINV + i];
    }
}

// ------------- update via MFMA; writes state + state-frags + ent_{t+1}-frags -------------
__global__ __launch_bounds__(256) void update_mfma_kernel(const float* __restrict__ cand,
                                                          const float* __restrict__ xg2,
                                                          const unsigned short* __restrict__ WuF,
                                                          const float* __restrict__ bu,
                                                          const float* __restrict__ rbuf,
                                                          float* __restrict__ state,
                                                          unsigned short* __restrict__ Xf,
                                                          const float* __restrict__ ent,
                                                          int tnext) {
    __shared__ unsigned short A_h[16 * 168], A_l[16 * 168];
    const int n = blockIdx.x;
    const int tid = threadIdx.x;
    const int lane = tid & 63;
    const int w = tid >> 6;
    for (int idx = tid; idx < 16 * 36; idx += 256) {
        int b = idx / 36, k = 132 + idx - b * 36;
        A_h[b * 168 + k] = 0; A_l[b * 168 + k] = 0;
    }
    for (int idx = tid; idx < 16 * 132; idx += 256) {
        int b = idx / 132, ip = idx - b * 132;
        float v;
        if (ip < CIN) {
            v = cand[(size_t)b * NN * CIN + n * CIN + ip];
        } else {
            size_t g = (size_t)b * NN * CIN + n * CIN + (ip - CIN);
            v = xg2[g] + xg2[g + PART] + xg2[g + 2 * PART] + xg2[g + 3 * PART];
        }
        unsigned hi, lo;
        split_(v, hi, lo);
        A_h[b * 168 + ip] = (unsigned short)hi;
        A_l[b * 168 + ip] = (unsigned short)lo;
    }
    __syncthreads();

    f32x4 acc = {0.f, 0.f, 0.f, 0.f};
    const unsigned short* Wn = WuF + (size_t)n * (4 * 5 * 1024);
    #pragma unroll
    for (int kc = 0; kc < 5; kc++) {
        int aoff = (lane & 15) * 168 + kc * 32 + (lane >> 4) * 8;
        short8 ah = *(const short8*)&A_h[aoff];
        short8 al = *(const short8*)&A_l[aoff];
        const unsigned short* f0 = Wn + ((size_t)(w * 5) + kc) * 1024 + lane * 8;
        short8 bh = *(const short8*)f0;
        short8 bl = *(const short8*)(f0 + 512);
        acc = __builtin_amdgcn_mfma_f32_16x16x32_bf16(ah, bh, acc, 0, 0, 0);
        acc = __builtin_amdgcn_mfma_f32_16x16x32_bf16(ah, bl, acc, 0, 0, 0);
        acc = __builtin_amdgcn_mfma_f32_16x16x32_bf16(al, bh, acc, 0, 0, 0);
    }
    const int col = lane & 15, rq = lane >> 4;
    const int q = n >> 6, kcn = (n >> 5) & 1, jn = n & 7;
    int o = w * 16 + col;
    int c = o + DINV;
    int ct = c >> 4, cl = c & 15;
    int l = ((n >> 3) & 3) * 16 + cl;
    float bias = bu[n * HH + o];
    #pragma unroll
    for (int reg = 0; reg < 4; reg++) {
        int b = rq * 4 + reg;
        float hc = tanhf_(acc[reg] + bias);
        size_t g = ((size_t)b * NN + n) * HH + o;
        float rr = rbuf[g];
        float ns = rr * state[g] + (1.f - rr) * hc;
        state[g] = ns;
        unsigned hi, lo;
        split_(ns, hi, lo);
        size_t fb = ((((size_t)b * 8 + q) * 5 + ct) * 2 + kcn) << 10;
        Xf[fb + l * 8 + jn] = (unsigned short)hi;
        Xf[fb + 512 + l * 8 + jn] = (unsigned short)lo;
    }
    if (w == 0 && col < DINV && tnext < TT) {
        int le = ((n >> 3) & 3) * 16 + col;
        #pragma unroll
        for (int reg = 0; reg < 4; reg++) {
            int b = rq * 4 + reg;
            float v = ent[((size_t)(b * TT + tnext) * NN + n) * DINV + col];
            unsigned hi, lo;
            split_(v, hi, lo);
            size_t fb = ((((size_t)b * 8 + q) * 5 + 0) * 2 + kcn) << 10;
            Xf[fb + le * 8 + jn] = (unsigned short)hi;
            Xf[fb + 512 + le * 8 + jn] = (unsigned short)lo;
        }
    }
}

// ------------- fused 2-layer LSTM: f16-packed operands + v_dot2 -------------
__global__ __launch_bounds__(512) void lstm_fused_kernel(
    const float* __restrict__ sr,
    const unsigned* __restrict__ wp_ih0, const float* __restrict__ Wih0,
    const float* __restrict__ bih0, const float* __restrict__ bhh0,
    const unsigned* __restrict__ wp_hh0, const float* __restrict__ Whh0,
    const unsigned* __restrict__ wp_ih1, const float* __restrict__ Wih1,
    const float* __restrict__ bih1, const float* __restrict__ bhh1,
    const unsigned* __restrict__ wp_hh1, const float* __restrict__ Whh1,
    float* __restrict__ h2last) {
    const int b = blockIdx.x;
    const int tid = threadIdx.x;
    const int lane = tid & 63;
    const int wv = tid >> 6;
    __shared__ __align__(16) float xp[32 * 520];        // gate preacts (f32)
    __shared__ __align__(16) unsigned h1p[32 * 68];     // packed f16 h1 pairs
    __shared__ __align__(16) float h1s[32 * 132];       // f32 h1 (extra-gate path)
    __shared__ __align__(16) unsigned xsp[32 * 32];     // packed f16 x pairs
    __shared__ __align__(16) unsigned hP[68];           // packed f16 h pairs
    __shared__ __align__(16) float hS[132], cS[132];
    __shared__ float gS[520];
    __shared__ float WeX[130 * 8];
    unsigned wpk[65];

    // ===== stage packed x, Wih0 =====
    for (int l = tid; l < 32 * 32; l += 512) {
        float2 v = *(const float2*)&sr[(size_t)b * 2048 + 2 * l];
        xsp[l] = pkh_(v.x, v.y);
    }
    #pragma unroll
    for (int kk = 0; kk < 32; kk++) wpk[kk] = wp_ih0[kk * 520 + tid];
    for (int l = tid; l < 64 * 8; l += 512) { int k = l >> 3, je = l & 7; WeX[l] = Wih0[(512 + je) * 64 + k]; }
    __syncthreads();
    // ===== L0 x-projection =====
    {
        float bias = bih0[tid] + bhh0[tid];
        for (int t = 0; t < 32; t++) {
            const uint4* x4 = (const uint4*)&xsp[t * 32];
            float a0 = bias, a1 = 0.f;
            #pragma unroll
            for (int q = 0; q < 8; q++) {
                uint4 hq = x4[q];
                a0 = fdot2_(hq.x, wpk[4 * q + 0], a0);
                a1 = fdot2_(hq.y, wpk[4 * q + 1], a1);
                a0 = fdot2_(hq.z, wpk[4 * q + 2], a0);
                a1 = fdot2_(hq.w, wpk[4 * q + 3], a1);
            }
            xp[t * 520 + tid] = a0 + a1;
        }
        if (tid < 256) {
            int je = tid & 7, t = tid >> 3;
            float a = bih0[512 + je] + bhh0[512 + je];
            for (int p = 0; p < 32; p++) {
                unsigned u = xsp[t * 32 + p];
                a += plo_(u) * WeX[(2 * p) * 8 + je] + phi_(u) * WeX[(2 * p + 1) * 8 + je];
            }
            xp[t * 520 + 512 + je] = a;
        }
    }
    __syncthreads();

    // ===== L0 recurrence =====
    #pragma unroll
    for (int kk = 0; kk < 65; kk++) wpk[kk] = wp_hh0[kk * 520 + tid];
    for (int l = tid; l < 130 * 8; l += 512) { int k = l >> 3, je = l & 7; WeX[l] = Whh0[(512 + je) * 130 + k]; }
    for (int l = tid; l < 132; l += 512) { hS[l] = 0.f; cS[l] = 0.f; }
    if (tid < 68) hP[tid] = 0u;
    __syncthreads();
    {
        float we0 = WeX[lane * 8 + wv];
        float we1 = WeX[(lane + 64) * 8 + wv];
        float we2 = (lane < 2) ? WeX[(lane + 128) * 8 + wv] : 0.f;
        for (int t = 0; t < 32; t++) {
            const uint4* hp4 = (const uint4*)hP;
            float a0 = xp[t * 520 + tid], a1 = 0.f;
            #pragma unroll
            for (int q = 0; q < 16; q++) {
                uint4 hq = hp4[q];
                a0 = fdot2_(hq.x, wpk[4 * q + 0], a0);
                a1 = fdot2_(hq.y, wpk[4 * q + 1], a1);
                a0 = fdot2_(hq.z, wpk[4 * q + 2], a0);
                a1 = fdot2_(hq.w, wpk[4 * q + 3], a1);
            }
            a0 = fdot2_(hP[64], wpk[64], a0);
            gS[tid] = a0 + a1;
            float p = hS[lane] * we0 + hS[lane + 64] * we1;
            if (lane < 2) p += hS[lane + 128] * we2;
            #pragma unroll
            for (int off = 32; off >= 1; off >>= 1) p += __shfl_xor(p, off);
            if (lane == 0) gS[512 + wv] = xp[t * 520 + 512 + wv] + p;
            __syncthreads();
            if (tid < 130) {
                float iv = sigmoidf_(gS[tid]);
                float fv = sigmoidf_(gS[130 + tid]);
                float gv = tanhf_(gS[260 + tid]);
                float ov = sigmoidf_(gS[390 + tid]);
                float cv = fv * cS[tid] + iv * gv;
                cS[tid] = cv;
                float hv = ov * tanhf_(cv);
                hS[tid] = hv;
                h1s[t * 132 + tid] = hv;
                float nb = __shfl_xor(hv, 1);
                if ((tid & 1) == 0) {
                    unsigned pk = pkh_(hv, nb);
                    hP[tid >> 1] = pk;
                    h1p[t * 68 + (tid >> 1)] = pk;
                }
            }
            __syncthreads();
        }
    }

    // ===== L1 x-projection (input = packed h1) =====
    #pragma unroll
    for (int kk = 0; kk < 65; kk++) wpk[kk] = wp_ih1[kk * 520 + tid];
    for (int l = tid; l < 130 * 8; l += 512) { int k = l >> 3, je = l & 7; WeX[l] = Wih1[(512 + je) * 130 + k]; }
    __syncthreads();
    {
        float bias = bih1[tid] + bhh1[tid];
        for (int t = 0; t < 32; t++) {
            const uint4* x4 = (const uint4*)&h1p[t * 68];
            float a0 = bias, a1 = 0.f;
            #pragma unroll
            for (int q = 0; q < 16; q++) {
                uint4 hq = x4[q];
                a0 = fdot2_(hq.x, wpk[4 * q + 0], a0);
                a1 = fdot2_(hq.y, wpk[4 * q + 1], a1);
                a0 = fdot2_(hq.z, wpk[4 * q + 2], a0);
                a1 = fdot2_(hq.w, wpk[4 * q + 3], a1);
            }
            a0 = fdot2_(h1p[t * 68 + 64], wpk[64], a0);
            xp[t * 520 + tid] = a0 + a1;
        }
        if (tid < 256) {
            int je = tid & 7, t = tid >> 3;
            float a = bih1[512 + je] + bhh1[512 + je];
            for (int k = 0; k < 130; k++) a += h1s[t * 132 + k] * WeX[k * 8 + je];
            xp[t * 520 + 512 + je] = a;
        }
    }
    __syncthreads();

    // ===== L1 recurrence =====
    #pragma unroll
    for (int kk = 0; kk < 65; kk++) wpk[kk] = wp_hh1[kk * 520 + tid];
    for (int l = tid; l < 130 * 8; l += 512) { int k = l >> 3, je = l & 7; WeX[l] = Whh1[(512 + je) * 130 + k]; }
    for (int l = tid; l < 132; l += 512) { hS[l] = 0.f; cS[l] = 0.f; }
    if (tid < 68) hP[tid] = 0u;
    __syncthreads();
    {
        float we0 = WeX[lane * 8 + wv];
        float we1 = WeX[(lane + 64) * 8 + wv];
        float we2 = (lane < 2) ? WeX[(lane + 128) * 8 + wv] : 0.f;
        for (int t = 0; t < 32; t++) {
            const uint4* hp4 = (const uint4*)hP;
            float a0 = xp[t * 520 + tid], a1 = 0.f;
            #pragma unroll
            for (int q = 0; q < 16; q++) {
                uint4 hq = hp4[q];
                a0 = fdot2_(hq.x, wpk[4 * q + 0], a0);
                a1 = fdot2_(hq.y, wpk[4 * q + 1], a1);
                a0 = fdot2_(hq.z, wpk[4 * q + 2], a0);
                a1 = fdot2_(hq.w, wpk[4 * q + 3], a1);
            }
            a0 = fdot2_(hP[64], wpk[64], a0);
            gS[tid] = a0 + a1;
            float p = hS[lane] * we0 + hS[lane + 64] * we1;
            if (lane < 2) p += hS[lane + 128] * we2;
            #pragma unroll
            for (int off = 32; off >= 1; off >>= 1) p += __shfl_xor(p, off);
            if (lane == 0) gS[512 + wv] = xp[t * 520 + 512 + wv] + p;
            __syncthreads();
            if (tid < 130) {
                float iv = sigmoidf_(gS[tid]);
                float fv = sigmoidf_(gS[130 + tid]);
                float gv = tanhf_(gS[260 + tid]);
                float ov = sigmoidf_(gS[390 + tid]);
                float cv = fv * cS[tid] + iv * gv;
                cS[tid] = cv;
                float hv = ov * tanhf_(cv);
                hS[tid] = hv;
                float nb = __shfl_xor(hv, 1);
                if ((tid & 1) == 0) hP[tid >> 1] = pkh_(hv, nb);
                if (t == 31) h2last[(size_t)b * LH + tid] = hv;
            }
            __syncthreads();
        }
    }
}

// ------------- final -------------
__global__ __launch_bounds__(256) void final_kernel(const float* __restrict__ state,
                                                    const float* __restrict__ h2last,
                                                    const float* __restrict__ fcW,
                                                    const float* __restrict__ fcb,
                                                    float* __restrict__ out) {
    const int b = blockIdx.x;
    const int tid = threadIdx.x;
    __shared__ float feat[LH + HH];
    __shared__ float red[4][HH];
    const int hh = tid & 63, q = tid >> 6;
    float mx = -INFINITY;
    for (int n = q * 128; n < q * 128 + 128; n++)
        mx = fmaxf(mx, state[((size_t)b * NN + n) * HH + hh]);
    red[q][hh] = mx;
    if (tid >= 64 && tid < 64 + LH)
        feat[tid - 64] = h2last[(size_t)b * LH + (tid - 64)];
    __syncthreads();
    if (tid < HH)
        feat[LH + tid] = fmaxf(fmaxf(red[0][tid], red[1][tid]), fmaxf(red[2][tid], red[3][tid]));
    __syncthreads();
    if (tid < 24) {
        float a = fcb[tid];
        for (int k = 0; k < LH + HH; k++) a += feat[k] * fcW[tid * (LH + HH) + k];
        out[b * 24 + tid] = sigmoidf_(a);
    }
}

extern "C" void kernel_launch(void* const* d_in, const int* in_sizes, int n_in,
                              void* d_out, int out_size, void* d_ws, size_t ws_size,
                              hipStream_t stream) {
    const float* ent  = (const float*)d_in[0];
    const float* mask = (const float*)d_in[1];
    const float* sr   = (const float*)d_in[2];
    const float* emb  = (const float*)d_in[3];
    const float* gW   = (const float*)d_in[4];
    const float* gb   = (const float*)d_in[5];
    const float* uW   = (const float*)d_in[6];
    const float* ub   = (const float*)d_in[7];
    const float* Wih0 = (const float*)d_in[8];
    const float* Whh0 = (const float*)d_in[9];
    const float* bih0 = (const float*)d_in[10];
    const float* bhh0 = (const float*)d_in[11];
    const float* Wih1 = (const float*)d_in[12];
    const float* Whh1 = (const float*)d_in[13];
    const float* bih1 = (const float*)d_in[14];
    const float* bhh1 = (const float*)d_in[15];
    const float* fcW  = (const float*)d_in[16];
    const float* fcb  = (const float*)d_in[17];
    float* out = (float*)d_out;
    float* ws = (float*)d_ws;

    size_t off = 0;
    float* Sb     = ws + off; off += (size_t)NN * NN;
    unsigned short* WgF = (unsigned short*)(ws + off); off += (size_t)NN * 8 * 5 * 512;
    unsigned short* WuF = (unsigned short*)(ws + off); off += (size_t)NN * 4 * 5 * 512;
    float* bgc    = ws + off; off += (size_t)NN * 128;
    float* buc    = ws + off; off += (size_t)NN * HH;
    float* state  = ws + off; off += (size_t)BB * NN * HH;
    float* xgP    = ws + off; off += 4 * PART;
    float* cand   = ws + off; off += PART;
    float* rbuf   = ws + off; off += (size_t)BB * NN * HH;
    float* h2last = ws + off; off += (size_t)BB * LH;
    unsigned short* Xf = (unsigned short*)(ws + off); off += (size_t)BB * 8 * 5 * 2 * 512;
    unsigned* wp_ih0 = (unsigned*)(ws + off); off += 32 * LG;
    unsigned* wp_hh0 = (unsigned*)(ws + off); off += 65 * LG;
    unsigned* wp_ih1 = (unsigned*)(ws + off); off += 65 * LG;
    unsigned* wp_hh1 = (unsigned*)(ws + off); off += 65 * LG;

    // ---- one-time precompute ----
    sbase_kernel<<<NN, 256, 0, stream>>>(emb, Sb);
    combine_frag_kernel<<<20480, 256, 0, stream>>>(emb, gW, WgF, 128, 8);
    combine_frag_kernel<<<20480, 256, 0, stream>>>(emb, uW, WuF, 64, 4);
    combine_kernel<<<256, 256, 0, stream>>>(emb, gb, bgc, 128, NN * 128);
    combine_kernel<<<128, 256, 0, stream>>>(emb, ub, buc, HH, NN * HH);
    pack_kernel<<<(32 * LG + 255) / 256, 256, 0, stream>>>(Wih0, wp_ih0, 64);
    pack_kernel<<<(65 * LG + 255) / 256, 256, 0, stream>>>(Whh0, wp_hh0, 130);
    pack_kernel<<<(65 * LG + 255) / 256, 256, 0, stream>>>(Wih1, wp_ih1, 130);
    pack_kernel<<<(65 * LG + 255) / 256, 256, 0, stream>>>(Whh1, wp_hh1, 130);
    zero_kernel<<<(BB * NN * HH + 255) / 256, 256, 0, stream>>>(state, BB * NN * HH);
    xfrag_kernel<<<320, 256, 0, stream>>>(ent, state, Xf, 0);

    // ---- GRU over 12 timesteps (4 dispatches each) ----
    for (int t = 0; t < TT; t++) {
        spmm_kernel<<<dim3(8, BB, 4), 256, 0, stream>>>(Sb, mask, Xf, xgP, t);
        gate_mfma_kernel<<<NN, 256, 0, stream>>>(ent, state, xgP, WgF, bgc, cand, rbuf, Xf, t);
        spmm_kernel<<<dim3(8, BB, 4), 256, 0, stream>>>(Sb, mask, Xf, xgP, t);
        update_mfma_kernel<<<NN, 256, 0, stream>>>(cand, xgP, WuF, buc, rbuf, state, Xf, ent, t + 1);
    }

    // ---- fused LSTM stack ----
    lstm_fused_kernel<<<BB, 512, 0, stream>>>(sr, wp_ih0, Wih0, bih0, bhh0, wp_hh0, Whh0,
                                              wp_ih1, Wih1, bih1, bhh1, wp_hh1, Whh1, h2last);

    // ---- final ----
    final_kernel<<<BB, 256, 0, stream>>>(state, h2last, fcW, fcb, out);
}

// Round 12
// 838.782 us; speedup vs baseline: 3.0487x; 1.1789x over previous
//
#include <hip/hip_runtime.h>
#include <math.h>

#define NN 512
#define EMBD 10
#define HH 64
#define DINV 2
#define CIN 66
#define TT 12
#define BB 16
#define LH 130
#define LG 520
#define PART ((size_t)BB * NN * CIN)

typedef __attribute__((ext_vector_type(8))) short short8;
typedef __attribute__((ext_vector_type(8))) _Float16 half8;
typedef __attribute__((ext_vector_type(4))) float f32x4;
typedef __attribute__((ext_vector_type(2))) _Float16 h2v;

__device__ __forceinline__ float sigmoidf_(float x) { return 1.f / (1.f + __expf(-x)); }
__device__ __forceinline__ float tanhf_(float x)    { return 1.f - 2.f / (1.f + __expf(2.f * x)); }
__device__ __forceinline__ unsigned short f16u_(float v) {
    return __builtin_bit_cast(unsigned short, (_Float16)v);
}
__device__ __forceinline__ unsigned pkh_(float a, float b) {
    return (unsigned)f16u_(a) | ((unsigned)f16u_(b) << 16);
}
__device__ __forceinline__ float fdot2_(unsigned h, unsigned w, float c) {
#if __has_builtin(__builtin_amdgcn_fdot2)
    return __builtin_amdgcn_fdot2(__builtin_bit_cast(h2v, h), __builtin_bit_cast(h2v, w), c, false);
#else
    h2v H = __builtin_bit_cast(h2v, h), W = __builtin_bit_cast(h2v, w);
    return c + (float)H[0] * (float)W[0] + (float)H[1] * (float)W[1];
#endif
}
__device__ __forceinline__ float plo_(unsigned u) { return (float)__builtin_bit_cast(h2v, u)[0]; }
__device__ __forceinline__ float phi_(unsigned u) { return (float)__builtin_bit_cast(h2v, u)[1]; }
__device__ __forceinline__ half8 ld8h_(const unsigned short* p) {
    return __builtin_bit_cast(half8, *(const short8*)p);
}

// ---------------- S_base = softmax(relu(emb @ emb^T)) ----------------
__global__ __launch_bounds__(256) void sbase_kernel(const float* __restrict__ emb,
                                                    float* __restrict__ Sb) {
    const int n = blockIdx.x;
    const int tid = threadIdx.x;
    __shared__ float en[EMBD];
    __shared__ float redw[4];
    if (tid < EMBD) en[tid] = emb[n * EMBD + tid];
    __syncthreads();
    float v[2];
    #pragma unroll
    for (int q = 0; q < 2; q++) {
        int m = tid + q * 256;
        float s = 0.f;
        #pragma unroll
        for (int d = 0; d < EMBD; d++) s += en[d] * emb[m * EMBD + d];
        v[q] = fmaxf(s, 0.f);
    }
    float mx = fmaxf(v[0], v[1]);
    for (int off = 32; off >= 1; off >>= 1) mx = fmaxf(mx, __shfl_xor(mx, off));
    if ((tid & 63) == 0) redw[tid >> 6] = mx;
    __syncthreads();
    mx = fmaxf(fmaxf(redw[0], redw[1]), fmaxf(redw[2], redw[3]));
    __syncthreads();
    v[0] = __expf(v[0] - mx);
    v[1] = __expf(v[1] - mx);
    float sm = v[0] + v[1];
    for (int off = 32; off >= 1; off >>= 1) sm += __shfl_xor(sm, off);
    if ((tid & 63) == 0) redw[tid >> 6] = sm;
    __syncthreads();
    sm = redw[0] + redw[1] + redw[2] + redw[3];
    float inv = 1.f / sm;
    Sb[n * NN + tid]       = v[0] * inv;
    Sb[n * NN + tid + 256] = v[1] * inv;
}

// ------------- per-node biases (f32) -------------
__global__ __launch_bounds__(256) void combine_kernel(const float* __restrict__ emb,
                                                      const float* __restrict__ pool,
                                                      float* __restrict__ out,
                                                      int per_n, int total) {
    for (int idx = blockIdx.x * 256 + threadIdx.x; idx < total; idx += gridDim.x * 256) {
        int n = idx / per_n;
        int rem = idx - n * per_n;
        float a = 0.f;
        #pragma unroll
        for (int d = 0; d < EMBD; d++) a += emb[n * EMBD + d] * pool[d * per_n + rem];
        out[idx] = a;
    }
}

// ------------- per-node weights -> fragment-ordered f16 (single plane) -------------
__global__ __launch_bounds__(256) void combine_frag_kernel(const float* __restrict__ emb,
                                                           const float* __restrict__ pool,
                                                           unsigned short* __restrict__ outU,
                                                           int O, int OT) {
    size_t total = (size_t)NN * OT * 5 * 512;
    for (size_t idx = (size_t)blockIdx.x * 256 + threadIdx.x; idx < total;
         idx += (size_t)gridDim.x * 256) {
        int j = idx & 7;
        int l = (idx >> 3) & 63;
        size_t r = idx >> 9;
        int kc = (int)(r % 5); r /= 5;
        int ot = (int)(r % OT);
        int n  = (int)(r / OT);
        int kp = kc * 32 + ((l >> 4) << 3) + j;
        int o = ot * 16 + (l & 15);
        float v = 0.f;
        if (kp < 2 * CIN) {
            int kk = (kp >= CIN) ? 1 : 0;
            int i = kp - CIN * kk;
            const float* p = pool + ((size_t)(kk * CIN + i)) * O + o;
            #pragma unroll
            for (int d = 0; d < EMBD; d++)
                v += emb[n * EMBD + d] * p[(size_t)d * (2 * CIN) * O];
        }
        outU[idx] = f16u_(v);
    }
}

// ------------- pack LSTM weights: f16x2 pairs along k, layout [kk][520] -------------
__global__ __launch_bounds__(256) void pack_kernel(const float* __restrict__ w,
                                                   unsigned* __restrict__ wp, int K) {
    int idx = blockIdx.x * 256 + threadIdx.x;
    int KH = K >> 1;
    if (idx < KH * LG) {
        int kk = idx / LG, j = idx - kk * LG;
        wp[idx] = pkh_(w[j * K + 2 * kk], w[j * K + 2 * kk + 1]);
    }
}

__global__ __launch_bounds__(256) void zero_kernel(float* __restrict__ p, int n) {
    int i = blockIdx.x * 256 + threadIdx.x;
    if (i < n) p[i] = 0.f;
}

// ------------- A = Sb*mask -> f16 frags for ALL 12 timesteps -------------
// frag(b,t,ntile,mch): element (lane l, j): n = ntile*16+(l&15), m = mch*32+((l>>4)&3)*8+j
// AF ushort offset = global thread idx * 8  (perfectly coalesced stores)
__global__ __launch_bounds__(256) void afrag_kernel(const float* __restrict__ Sb,
                                                    const float* __restrict__ mask,
                                                    unsigned short* __restrict__ AF) {
    size_t idx = (size_t)blockIdx.x * 256 + threadIdx.x;   // 6,291,456 threads
    int l = (int)(idx & 63);
    size_t f = idx >> 6;
    int mch = (int)(f & 15); f >>= 4;
    int ntile = (int)(f & 31); f >>= 5;
    int t = (int)(f % 12);
    int b = (int)(f / 12);
    int nrow = ntile * 16 + (l & 15);
    int m0 = mch * 32 + ((l >> 4) & 3) * 8;
    const float4* s4 = (const float4*)(Sb + (size_t)nrow * NN + m0);
    const float4* m4 = (const float4*)(mask + ((size_t)(b * TT + t) * NN + nrow) * NN + m0);
    float4 sa = s4[0], sc = s4[1];
    float4 ma = m4[0], mc = m4[1];
    union { unsigned short u[8]; short8 v; } o;
    o.u[0] = f16u_(sa.x * ma.x); o.u[1] = f16u_(sa.y * ma.y);
    o.u[2] = f16u_(sa.z * ma.z); o.u[3] = f16u_(sa.w * ma.w);
    o.u[4] = f16u_(sc.x * mc.x); o.u[5] = f16u_(sc.y * mc.y);
    o.u[6] = f16u_(sc.z * mc.z); o.u[7] = f16u_(sc.w * mc.w);
    *(short8*)(AF + idx * 8) = o.v;
}

// ------------- init f16 frags of X (t=0: ent_0 + zero state) -------------
__global__ __launch_bounds__(256) void xfrag_kernel(const float* __restrict__ ent,
                                                    const float* __restrict__ state,
                                                    unsigned short* __restrict__ Xf,
                                                    int t) {
    int idx = blockIdx.x * 256 + threadIdx.x;   // 81,920 threads = 320 blocks
    int l = idx & 63;
    int r = idx >> 6;
    int kc = r & 1; r >>= 1;
    int ct = r % 5; r /= 5;
    int q = r & 7;
    int b = r >> 3;
    const int c = ct * 16 + (l & 15);
    const int mbase = q * 64 + kc * 32 + ((l >> 4) & 3) * 8;
    union { unsigned short u[8]; short8 v; } o;
    #pragma unroll
    for (int j = 0; j < 8; j++) {
        int m = mbase + j;
        float v = 0.f;
        if (c < CIN) {
            v = (c < DINV) ? ent[((size_t)(b * TT + t) * NN + m) * DINV + c]
                           : state[((size_t)b * NN + m) * HH + (c - DINV)];
        }
        o.u[j] = f16u_(v);
    }
    size_t base = ((((size_t)b * 8 + q) * 5 + ct) * 2 + kc) * 512;
    *(short8*)(Xf + base + l * 8) = o.v;
}

// ------------- spmm: pure f16 MFMA, no LDS, no barriers. grid (8, 16, 4) -------------
__global__ __launch_bounds__(256) void spmm_kernel(const unsigned short* __restrict__ AF,
                                                   const unsigned short* __restrict__ Xf,
                                                   float* __restrict__ out, int t) {
    const int tid = threadIdx.x;
    const int lane = tid & 63;
    const int w = tid >> 6;
    const int b = blockIdx.y;
    const int z = blockIdx.z;
    float* __restrict__ outp = out + (size_t)z * PART;
    const int ntile = blockIdx.x * 4 + w;

    f32x4 acc[5];
    #pragma unroll
    for (int ct = 0; ct < 5; ct++) acc[ct] = (f32x4){0.f, 0.f, 0.f, 0.f};

    #pragma unroll
    for (int r2 = 0; r2 < 2; r2++) {
        #pragma unroll
        for (int kc = 0; kc < 2; kc++) {
            const int mch = z * 4 + r2 * 2 + kc;
            const int q = z * 2 + r2;
            half8 a = ld8h_(AF + ((((size_t)b * TT + t) * 32 + ntile) * 16 + mch) * 512 + lane * 8);
            #pragma unroll
            for (int ct = 0; ct < 5; ct++) {
                half8 bf = ld8h_(Xf + ((((size_t)b * 8 + q) * 5 + ct) * 2 + kc) * 512 + lane * 8);
                acc[ct] = __builtin_amdgcn_mfma_f32_16x16x32_f16(a, bf, acc[ct], 0, 0, 0);
            }
        }
    }
    const int col = lane & 15, rq = lane >> 4;
    #pragma unroll
    for (int ct = 0; ct < 5; ct++) {
        int c = ct * 16 + col;
        if (c < CIN) {
            #pragma unroll
            for (int reg = 0; reg < 4; reg++) {
                int n = ntile * 16 + rq * 4 + reg;
                outp[(size_t)b * NN * CIN + n * CIN + c] = acc[ct][reg];
            }
        }
    }
}

// ------------- gate via f16 MFMA; writes cand-frags into Xf -------------
__global__ __launch_bounds__(256) void gate_mfma_kernel(const float* __restrict__ ent,
                                                        const float* __restrict__ state,
                                                        const float* __restrict__ xg1,
                                                        const unsigned short* __restrict__ WgF,
                                                        const float* __restrict__ bg,
                                                        float* __restrict__ cand,
                                                        float* __restrict__ rbuf,
                                                        unsigned short* __restrict__ Xf,
                                                        int t) {
    __shared__ unsigned short A_h[16 * 168];
    const int n = blockIdx.x;
    const int tid = threadIdx.x;
    const int lane = tid & 63;
    const int w = tid >> 6;
    for (int idx = tid; idx < 16 * 36; idx += 256) {
        int b = idx / 36, k = 132 + idx - b * 36;
        A_h[b * 168 + k] = 0;
    }
    for (int idx = tid; idx < 16 * 132; idx += 256) {
        int b = idx / 132, ip = idx - b * 132;
        float v;
        if (ip < CIN) {
            v = (ip < DINV) ? ent[((size_t)(b * TT + t) * NN + n) * DINV + ip]
                            : state[((size_t)b * NN + n) * HH + (ip - DINV)];
        } else {
            size_t g = (size_t)b * NN * CIN + n * CIN + (ip - CIN);
            v = xg1[g] + xg1[g + PART] + xg1[g + 2 * PART] + xg1[g + 3 * PART];
        }
        A_h[b * 168 + ip] = f16u_(v);
    }
    __syncthreads();

    f32x4 acc0 = {0.f, 0.f, 0.f, 0.f}, acc1 = {0.f, 0.f, 0.f, 0.f};
    const unsigned short* Wn = WgF + (size_t)n * (8 * 5 * 512);
    #pragma unroll
    for (int kc = 0; kc < 5; kc++) {
        int aoff = (lane & 15) * 168 + kc * 32 + (lane >> 4) * 8;
        half8 ah = ld8h_(&A_h[aoff]);
        half8 bh0 = ld8h_(Wn + ((size_t)(w * 5) + kc) * 512 + lane * 8);
        half8 bh1 = ld8h_(Wn + ((size_t)((w + 4) * 5) + kc) * 512 + lane * 8);
        acc0 = __builtin_amdgcn_mfma_f32_16x16x32_f16(ah, bh0, acc0, 0, 0, 0);
        acc1 = __builtin_amdgcn_mfma_f32_16x16x32_f16(ah, bh1, acc1, 0, 0, 0);
    }
    const int col = lane & 15, rq = lane >> 4;
    const int q = n >> 6, kcn = (n >> 5) & 1, jn = n & 7;
    {
        int o = w * 16 + col;
        int c = o + DINV;
        int ct = c >> 4, cl = c & 15;
        int l = ((n >> 3) & 3) * 16 + cl;
        float bias = bg[n * 128 + o];
        #pragma unroll
        for (int reg = 0; reg < 4; reg++) {
            int b = rq * 4 + reg;
            float zr = sigmoidf_(acc0[reg] + bias);
            float val = zr * state[((size_t)b * NN + n) * HH + o];
            cand[(size_t)b * NN * CIN + n * CIN + c] = val;
            size_t fb = ((((size_t)b * 8 + q) * 5 + ct) * 2 + kcn) * 512;
            Xf[fb + l * 8 + jn] = f16u_(val);
        }
    }
    {
        int o = (w + 4) * 16 + col;
        float bias = bg[n * 128 + o];
        #pragma unroll
        for (int reg = 0; reg < 4; reg++) {
            int b = rq * 4 + reg;
            float zr = sigmoidf_(acc1[reg] + bias);
            rbuf[((size_t)b * NN + n) * HH + (o - HH)] = zr;
        }
    }
    if (tid < 32) {
        int b = tid >> 1, i = tid & 1;
        cand[(size_t)b * NN * CIN + n * CIN + i] =
            ent[((size_t)(b * TT + t) * NN + n) * DINV + i];
    }
}

// ------------- update via f16 MFMA; writes state + state-frags + ent_{t+1}-frags -------------
__global__ __launch_bounds__(256) void update_mfma_kernel(const float* __restrict__ cand,
                                                          const float* __restrict__ xg2,
                                                          const unsigned short* __restrict__ WuF,
                                                          const float* __restrict__ bu,
                                                          const float* __restrict__ rbuf,
                                                          float* __restrict__ state,
                                                          unsigned short* __restrict__ Xf,
                                                          const float* __restrict__ ent,
                                                          int tnext) {
    __shared__ unsigned short A_h[16 * 168];
    const int n = blockIdx.x;
    const int tid = threadIdx.x;
    const int lane = tid & 63;
    const int w = tid >> 6;
    for (int idx = tid; idx < 16 * 36; idx += 256) {
        int b = idx / 36, k = 132 + idx - b * 36;
        A_h[b * 168 + k] = 0;
    }
    for (int idx = tid; idx < 16 * 132; idx += 256) {
        int b = idx / 132, ip = idx - b * 132;
        float v;
        if (ip < CIN) {
            v = cand[(size_t)b * NN * CIN + n * CIN + ip];
        } else {
            size_t g = (size_t)b * NN * CIN + n * CIN + (ip - CIN);
            v = xg2[g] + xg2[g + PART] + xg2[g + 2 * PART] + xg2[g + 3 * PART];
        }
        A_h[b * 168 + ip] = f16u_(v);
    }
    __syncthreads();

    f32x4 acc = {0.f, 0.f, 0.f, 0.f};
    const unsigned short* Wn = WuF + (size_t)n * (4 * 5 * 512);
    #pragma unroll
    for (int kc = 0; kc < 5; kc++) {
        int aoff = (lane & 15) * 168 + kc * 32 + (lane >> 4) * 8;
        half8 ah = ld8h_(&A_h[aoff]);
        half8 bh = ld8h_(Wn + ((size_t)(w * 5) + kc) * 512 + lane * 8);
        acc = __builtin_amdgcn_mfma_f32_16x16x32_f16(ah, bh, acc, 0, 0, 0);
    }
    const int col = lane & 15, rq = lane >> 4;
    const int q = n >> 6, kcn = (n >> 5) & 1, jn = n & 7;
    int o = w * 16 + col;
    int c = o + DINV;
    int ct = c >> 4, cl = c & 15;
    int l = ((n >> 3) & 3) * 16 + cl;
    float bias = bu[n * HH + o];
    #pragma unroll
    for (int reg = 0; reg < 4; reg++) {
        int b = rq * 4 + reg;
        float hc = tanhf_(acc[reg] + bias);
        size_t g = ((size_t)b * NN + n) * HH + o;
        float rr = rbuf[g];
        float ns = rr * state[g] + (1.f - rr) * hc;
        state[g] = ns;
        size_t fb = ((((size_t)b * 8 + q) * 5 + ct) * 2 + kcn) * 512;
        Xf[fb + l * 8 + jn] = f16u_(ns);
    }
    if (w == 0 && col < DINV && tnext < TT) {
        int le = ((n >> 3) & 3) * 16 + col;
        #pragma unroll
        for (int reg = 0; reg < 4; reg++) {
            int b = rq * 4 + reg;
            float v = ent[((size_t)(b * TT + tnext) * NN + n) * DINV + col];
            size_t fb = ((((size_t)b * 8 + q) * 5 + 0) * 2 + kcn) * 512;
            Xf[fb + le * 8 + jn] = f16u_(v);
        }
    }
}

// ------------- fused 2-layer LSTM: f16-packed operands + v_dot2 (round-11 winner) -------------
__global__ __launch_bounds__(512) void lstm_fused_kernel(
    const float* __restrict__ sr,
    const unsigned* __restrict__ wp_ih0, const float* __restrict__ Wih0,
    const float* __restrict__ bih0, const float* __restrict__ bhh0,
    const unsigned* __restrict__ wp_hh0, const float* __restrict__ Whh0,
    const unsigned* __restrict__ wp_ih1, const float* __restrict__ Wih1,
    const float* __restrict__ bih1, const float* __restrict__ bhh1,
    const unsigned* __restrict__ wp_hh1, const float* __restrict__ Whh1,
    float* __restrict__ h2last) {
    const int b = blockIdx.x;
    const int tid = threadIdx.x;
    const int lane = tid & 63;
    const int wv = tid >> 6;
    __shared__ __align__(16) float xp[32 * 520];
    __shared__ __align__(16) unsigned h1p[32 * 68];
    __shared__ __align__(16) float h1s[32 * 132];
    __shared__ __align__(16) unsigned xsp[32 * 32];
    __shared__ __align__(16) unsigned hP[68];
    __shared__ __align__(16) float hS[132], cS[132];
    __shared__ float gS[520];
    __shared__ float WeX[130 * 8];
    unsigned wpk[65];

    for (int l = tid; l < 32 * 32; l += 512) {
        float2 v = *(const float2*)&sr[(size_t)b * 2048 + 2 * l];
        xsp[l] = pkh_(v.x, v.y);
    }
    #pragma unroll
    for (int kk = 0; kk < 32; kk++) wpk[kk] = wp_ih0[kk * 520 + tid];
    for (int l = tid; l < 64 * 8; l += 512) { int k = l >> 3, je = l & 7; WeX[l] = Wih0[(512 + je) * 64 + k]; }
    __syncthreads();
    {
        float bias = bih0[tid] + bhh0[tid];
        for (int t = 0; t < 32; t++) {
            const uint4* x4 = (const uint4*)&xsp[t * 32];
            float a0 = bias, a1 = 0.f;
            #pragma unroll
            for (int q = 0; q < 8; q++) {
                uint4 hq = x4[q];
                a0 = fdot2_(hq.x, wpk[4 * q + 0], a0);
                a1 = fdot2_(hq.y, wpk[4 * q + 1], a1);
                a0 = fdot2_(hq.z, wpk[4 * q + 2], a0);
                a1 = fdot2_(hq.w, wpk[4 * q + 3], a1);
            }
            xp[t * 520 + tid] = a0 + a1;
        }
        if (tid < 256) {
            int je = tid & 7, t = tid >> 3;
            float a = bih0[512 + je] + bhh0[512 + je];
            for (int p = 0; p < 32; p++) {
                unsigned u = xsp[t * 32 + p];
                a += plo_(u) * WeX[(2 * p) * 8 + je] + phi_(u) * WeX[(2 * p + 1) * 8 + je];
            }
            xp[t * 520 + 512 + je] = a;
        }
    }
    __syncthreads();

    #pragma unroll
    for (int kk = 0; kk < 65; kk++) wpk[kk] = wp_hh0[kk * 520 + tid];
    for (int l = tid; l < 130 * 8; l += 512) { int k = l >> 3, je = l & 7; WeX[l] = Whh0[(512 + je) * 130 + k]; }
    for (int l = tid; l < 132; l += 512) { hS[l] = 0.f; cS[l] = 0.f; }
    if (tid < 68) hP[tid] = 0u;
    __syncthreads();
    {
        float we0 = WeX[lane * 8 + wv];
        float we1 = WeX[(lane + 64) * 8 + wv];
        float we2 = (lane < 2) ? WeX[(lane + 128) * 8 + wv] : 0.f;
        for (int t = 0; t < 32; t++) {
            const uint4* hp4 = (const uint4*)hP;
            float a0 = xp[t * 520 + tid], a1 = 0.f;
            #pragma unroll
            for (int q = 0; q < 16; q++) {
                uint4 hq = hp4[q];
                a0 = fdot2_(hq.x, wpk[4 * q + 0], a0);
                a1 = fdot2_(hq.y, wpk[4 * q + 1], a1);
                a0 = fdot2_(hq.z, wpk[4 * q + 2], a0);
                a1 = fdot2_(hq.w, wpk[4 * q + 3], a1);
            }
            a0 = fdot2_(hP[64], wpk[64], a0);
            gS[tid] = a0 + a1;
            float p = hS[lane] * we0 + hS[lane + 64] * we1;
            if (lane < 2) p += hS[lane + 128] * we2;
            #pragma unroll
            for (int off = 32; off >= 1; off >>= 1) p += __shfl_xor(p, off);
            if (lane == 0) gS[512 + wv] = xp[t * 520 + 512 + wv] + p;
            __syncthreads();
            if (tid < 130) {
                float iv = sigmoidf_(gS[tid]);
                float fv = sigmoidf_(gS[130 + tid]);
                float gv = tanhf_(gS[260 + tid]);
                float ov = sigmoidf_(gS[390 + tid]);
                float cv = fv * cS[tid] + iv * gv;
                cS[tid] = cv;
                float hv = ov * tanhf_(cv);
                hS[tid] = hv;
                h1s[t * 132 + tid] = hv;
                float nb = __shfl_xor(hv, 1);
                if ((tid & 1) == 0) {
                    unsigned pk = pkh_(hv, nb);
                    hP[tid >> 1] = pk;
                    h1p[t * 68 + (tid >> 1)] = pk;
                }
            }
            __syncthreads();
        }
    }

    #pragma unroll
    for (int kk = 0; kk < 65; kk++) wpk[kk] = wp_ih1[kk * 520 + tid];
    for (int l = tid; l < 130 * 8; l += 512) { int k = l >> 3, je = l & 7; WeX[l] = Wih1[(512 + je) * 130 + k]; }
    __syncthreads();
    {
        float bias = bih1[tid] + bhh1[tid];
        for (int t = 0; t < 32; t++) {
            const uint4* x4 = (const uint4*)&h1p[t * 68];
            float a0 = bias, a1 = 0.f;
            #pragma unroll
            for (int q = 0; q < 16; q++) {
                uint4 hq = x4[q];
                a0 = fdot2_(hq.x, wpk[4 * q + 0], a0);
                a1 = fdot2_(hq.y, wpk[4 * q + 1], a1);
                a0 = fdot2_(hq.z, wpk[4 * q + 2], a0);
                a1 = fdot2_(hq.w, wpk[4 * q + 3], a1);
            }
            a0 = fdot2_(h1p[t * 68 + 64], wpk[64], a0);
            xp[t * 520 + tid] = a0 + a1;
        }
        if (tid < 256) {
            int je = tid & 7, t = tid >> 3;
            float a = bih1[512 + je] + bhh1[512 + je];
            for (int k = 0; k < 130; k++) a += h1s[t * 132 + k] * WeX[k * 8 + je];
            xp[t * 520 + 512 + je] = a;
        }
    }
    __syncthreads();

    #pragma unroll
    for (int kk = 0; kk < 65; kk++) wpk[kk] = wp_hh1[kk * 520 + tid];
    for (int l = tid; l < 130 * 8; l += 512) { int k = l >> 3, je = l & 7; WeX[l] = Whh1[(512 + je) * 130 + k]; }
    for (int l = tid; l < 132; l += 512) { hS[l] = 0.f; cS[l] = 0.f; }
    if (tid < 68) hP[tid] = 0u;
    __syncthreads();
    {
        float we0 = WeX[lane * 8 + wv];
        float we1 = WeX[(lane + 64) * 8 + wv];
        float we2 = (lane < 2) ? WeX[(lane + 128) * 8 + wv] : 0.f;
        for (int t = 0; t < 32; t++) {
            const uint4* hp4 = (const uint4*)hP;
            float a0 = xp[t * 520 + tid], a1 = 0.f;
            #pragma unroll
            for (int q = 0; q < 16; q++) {
                uint4 hq = hp4[q];
                a0 = fdot2_(hq.x, wpk[4 * q + 0], a0);
                a1 = fdot2_(hq.y, wpk[4 * q + 1], a1);
                a0 = fdot2_(hq.z, wpk[4 * q + 2], a0);
                a1 = fdot2_(hq.w, wpk[4 * q + 3], a1);
            }
            a0 = fdot2_(hP[64], wpk[64], a0);
            gS[tid] = a0 + a1;
            float p = hS[lane] * we0 + hS[lane + 64] * we1;
            if (lane < 2) p += hS[lane + 128] * we2;
            #pragma unroll
            for (int off = 32; off >= 1; off >>= 1) p += __shfl_xor(p, off);
            if (lane == 0) gS[512 + wv] = xp[t * 520 + 512 + wv] + p;
            __syncthreads();
            if (tid < 130) {
                float iv = sigmoidf_(gS[tid]);
                float fv = sigmoidf_(gS[130 + tid]);
                float gv = tanhf_(gS[260 + tid]);
                float ov = sigmoidf_(gS[390 + tid]);
                float cv = fv * cS[tid] + iv * gv;
                cS[tid] = cv;
                float hv = ov * tanhf_(cv);
                hS[tid] = hv;
                float nb = __shfl_xor(hv, 1);
                if ((tid & 1) == 0) hP[tid >> 1] = pkh_(hv, nb);
                if (t == 31) h2last[(size_t)b * LH + tid] = hv;
            }
            __syncthreads();
        }
    }
}

// ------------- final -------------
__global__ __launch_bounds__(256) void final_kernel(const float* __restrict__ state,
                                                    const float* __restrict__ h2last,
                                                    const float* __restrict__ fcW,
                                                    const float* __restrict__ fcb,
                                                    float* __restrict__ out) {
    const int b = blockIdx.x;
    const int tid = threadIdx.x;
    __shared__ float feat[LH + HH];
    __shared__ float red[4][HH];
    const int hh = tid & 63, q = tid >> 6;
    float mx = -INFINITY;
    for (int n = q * 128; n < q * 128 + 128; n++)
        mx = fmaxf(mx, state[((size_t)b * NN + n) * HH + hh]);
    red[q][hh] = mx;
    if (tid >= 64 && tid < 64 + LH)
        feat[tid - 64] = h2last[(size_t)b * LH + (tid - 64)];
    __syncthreads();
    if (tid < HH)
        feat[LH + tid] = fmaxf(fmaxf(red[0][tid], red[1][tid]), fmaxf(red[2][tid], red[3][tid]));
    __syncthreads();
    if (tid < 24) {
        float a = fcb[tid];
        for (int k = 0; k < LH + HH; k++) a += feat[k] * fcW[tid * (LH + HH) + k];
        out[b * 24 + tid] = sigmoidf_(a);
    }
}

extern "C" void kernel_launch(void* const* d_in, const int* in_sizes, int n_in,
                              void* d_out, int out_size, void* d_ws, size_t ws_size,
                              hipStream_t stream) {
    const float* ent  = (const float*)d_in[0];
    const float* mask = (const float*)d_in[1];
    const float* sr   = (const float*)d_in[2];
    const float* emb  = (const float*)d_in[3];
    const float* gW   = (const float*)d_in[4];
    const float* gb   = (const float*)d_in[5];
    const float* uW   = (const float*)d_in[6];
    const float* ub   = (const float*)d_in[7];
    const float* Wih0 = (const float*)d_in[8];
    const float* Whh0 = (const float*)d_in[9];
    const float* bih0 = (const float*)d_in[10];
    const float* bhh0 = (const float*)d_in[11];
    const float* Wih1 = (const float*)d_in[12];
    const float* Whh1 = (const float*)d_in[13];
    const float* bih1 = (const float*)d_in[14];
    const float* bhh1 = (const float*)d_in[15];
    const float* fcW  = (const float*)d_in[16];
    const float* fcb  = (const float*)d_in[17];
    float* out = (float*)d_out;
    float* ws = (float*)d_ws;

    size_t off = 0;
    float* Sb     = ws + off; off += (size_t)NN * NN;
    unsigned short* WgF = (unsigned short*)(ws + off); off += (size_t)NN * 8 * 5 * 256;
    unsigned short* WuF = (unsigned short*)(ws + off); off += (size_t)NN * 4 * 5 * 256;
    unsigned short* AF  = (unsigned short*)(ws + off); off += (size_t)BB * TT * 32 * 16 * 256;
    float* bgc    = ws + off; off += (size_t)NN * 128;
    float* buc    = ws + off; off += (size_t)NN * HH;
    float* state  = ws + off; off += (size_t)BB * NN * HH;
    float* xgP    = ws + off; off += 4 * PART;
    float* cand   = ws + off; off += PART;
    float* rbuf   = ws + off; off += (size_t)BB * NN * HH;
    float* h2last = ws + off; off += (size_t)BB * LH;
    unsigned short* Xf = (unsigned short*)(ws + off); off += (size_t)BB * 8 * 5 * 2 * 256;
    unsigned* wp_ih0 = (unsigned*)(ws + off); off += 32 * LG;
    unsigned* wp_hh0 = (unsigned*)(ws + off); off += 65 * LG;
    unsigned* wp_ih1 = (unsigned*)(ws + off); off += 65 * LG;
    unsigned* wp_hh1 = (unsigned*)(ws + off); off += 65 * LG;

    // ---- one-time precompute ----
    sbase_kernel<<<NN, 256, 0, stream>>>(emb, Sb);
    combine_frag_kernel<<<10240, 256, 0, stream>>>(emb, gW, WgF, 128, 8);
    combine_frag_kernel<<<10240, 256, 0, stream>>>(emb, uW, WuF, 64, 4);
    combine_kernel<<<256, 256, 0, stream>>>(emb, gb, bgc, 128, NN * 128);
    combine_kernel<<<128, 256, 0, stream>>>(emb, ub, buc, HH, NN * HH);
    pack_kernel<<<(32 * LG + 255) / 256, 256, 0, stream>>>(Wih0, wp_ih0, 64);
    pack_kernel<<<(65 * LG + 255) / 256, 256, 0, stream>>>(Whh0, wp_hh0, 130);
    pack_kernel<<<(65 * LG + 255) / 256, 256, 0, stream>>>(Wih1, wp_ih1, 130);
    pack_kernel<<<(65 * LG + 255) / 256, 256, 0, stream>>>(Whh1, wp_hh1, 130);
    zero_kernel<<<(BB * NN * HH + 255) / 256, 256, 0, stream>>>(state, BB * NN * HH);
    afrag_kernel<<<24576, 256, 0, stream>>>(Sb, mask, AF);
    xfrag_kernel<<<320, 256, 0, stream>>>(ent, state, Xf, 0);

    // ---- GRU over 12 timesteps (4 dispatches each) ----
    for (int t = 0; t < TT; t++) {
        spmm_kernel<<<dim3(8, BB, 4), 256, 0, stream>>>(AF, Xf, xgP, t);
        gate_mfma_kernel<<<NN, 256, 0, stream>>>(ent, state, xgP, WgF, bgc, cand, rbuf, Xf, t);
        spmm_kernel<<<dim3(8, BB, 4), 256, 0, stream>>>(AF, Xf, xgP, t);
        update_mfma_kernel<<<NN, 256, 0, stream>>>(cand, xgP, WuF, buc, rbuf, state, Xf, ent, t + 1);
    }

    // ---- fused LSTM stack ----
    lstm_fused_kernel<<<BB, 512, 0, stream>>>(sr, wp_ih0, Wih0, bih0, bhh0, wp_hh0, Whh0,
                                              wp_ih1, Wih1, bih1, bhh1, wp_hh1, Whh1, h2last);

    // ---- final ----
    final_kernel<<<BB, 256, 0, stream>>>(state, h2last, fcW, fcb, out);
}